// Round 2
// baseline (4504.392 us; speedup 1.0000x reference)
//
#include <hip/hip_runtime.h>
#include <hip/hip_bf16.h>
#include <math.h>

// Problem constants
#define B_   4
#define L_   2048
#define DM_  1024
#define DS_  16
#define DC_  4
#define DI_  2048          // EXP * DM
#define DR_  64            // (DM+15)//16
#define MROWS (B_ * L_)    // 8192

// ---------------- Generic tiled fp32 GEMM:  C[MxN] = A[MxK] * B[NxK]^T ----------------
// EPI: 0 = plain store, 1 = softplus(acc + bias[n])
#define BM 128
#define BN 128
#define BK 16

__device__ inline float softplusf(float x) {
    return (x > 20.f) ? x : log1pf(expf(x));
}

template<int EPI>
__global__ __launch_bounds__(256) void gemm_bt(
    const float* __restrict__ A, const float* __restrict__ B, float* __restrict__ C,
    const float* __restrict__ bias, int M, int N, int K, int lda, int ldb, int ldc)
{
    __shared__ float As[BK][BM + 4];
    __shared__ float Bs[BK][BN + 4];

    const int tid = threadIdx.x;
    const int tx = tid & 15;        // 0..15  -> N dim
    const int ty = tid >> 4;        // 0..15  -> M dim
    const int m0 = blockIdx.x * BM;
    const int n0 = blockIdx.y * BN;

    float acc[8][8];
    #pragma unroll
    for (int i = 0; i < 8; ++i)
        #pragma unroll
        for (int j = 0; j < 8; ++j) acc[i][j] = 0.f;

    for (int k0 = 0; k0 < K; k0 += BK) {
        // Stage A tile (BM x BK) and B tile (BN x BK): 2048 elems each, 8 per thread
        #pragma unroll
        for (int i = 0; i < 8; ++i) {
            int e = tid + i * 256;      // 0..2047
            int mm = e >> 4;            // 0..127
            int kk = e & 15;            // 0..15
            int m = m0 + mm, k = k0 + kk;
            As[kk][mm] = (m < M && k < K) ? A[(size_t)m * lda + k] : 0.f;
            int n = n0 + mm;
            Bs[kk][mm] = (n < N && k < K) ? B[(size_t)n * ldb + k] : 0.f;
        }
        __syncthreads();

        #pragma unroll
        for (int kk = 0; kk < BK; ++kk) {
            float a[8], bb[8];
            #pragma unroll
            for (int i = 0; i < 8; ++i) a[i]  = As[kk][ty * 8 + i];
            #pragma unroll
            for (int j = 0; j < 8; ++j) bb[j] = Bs[kk][tx * 8 + j];
            #pragma unroll
            for (int i = 0; i < 8; ++i)
                #pragma unroll
                for (int j = 0; j < 8; ++j)
                    acc[i][j] = fmaf(a[i], bb[j], acc[i][j]);
        }
        __syncthreads();
    }

    // Epilogue
    #pragma unroll
    for (int i = 0; i < 8; ++i) {
        int m = m0 + ty * 8 + i;
        if (m >= M) continue;
        #pragma unroll
        for (int j = 0; j < 8; ++j) {
            int n = n0 + tx * 8 + j;
            if (n >= N) continue;
            float v = acc[i][j];
            if (EPI == 1) v = softplusf(v + bias[n]);
            C[(size_t)m * ldc + n] = v;
        }
    }
}

// ---------------- Depthwise causal conv (DC=4) + SiLU ----------------
// x = xz[..., :DI]; xc[b,l,d] = silu(conv_b[d] + sum_k x[b,l-3+k,d]*conv_w[d,k])
__global__ __launch_bounds__(256) void conv_silu_kernel(
    const float* __restrict__ xz, const float* __restrict__ cw,
    const float* __restrict__ cb, float* __restrict__ xc)
{
    int idx = blockIdx.x * 256 + threadIdx.x;           // over B*L*DI
    if (idx >= B_ * L_ * DI_) return;
    int d = idx & (DI_ - 1);
    int l = (idx >> 11) & (L_ - 1);
    int b = idx >> 22;

    float acc = cb[d];
    float w0 = cw[d * 4 + 0], w1 = cw[d * 4 + 1], w2 = cw[d * 4 + 2], w3 = cw[d * 4 + 3];
    size_t rowbase = (size_t)(b * L_) * (2 * DI_) + d;
    if (l >= 3) acc += xz[rowbase + (size_t)(l - 3) * (2 * DI_)] * w0;
    if (l >= 2) acc += xz[rowbase + (size_t)(l - 2) * (2 * DI_)] * w1;
    if (l >= 1) acc += xz[rowbase + (size_t)(l - 1) * (2 * DI_)] * w2;
    acc += xz[rowbase + (size_t)l * (2 * DI_)] * w3;

    float sig = 1.f / (1.f + __expf(-acc));
    xc[idx] = acc * sig;
}

// ---------------- Selective scan ----------------
// 4 lanes per (b,d): lane j handles states n = j*4 .. j*4+3.
// dt lives in the x-half of xz (cols 0..2047), z in cols 2048..4095.
// Writes y (gated) in-place over xc.
#define LCHUNK 128
__global__ __launch_bounds__(64) void scan_kernel(
    float* __restrict__ xc,
    const float* __restrict__ xz, const float* __restrict__ dbl,
    const float* __restrict__ A_log, const float* __restrict__ Dp)
{
    __shared__ float sBC[LCHUNK][32];   // [tt][0..15]=B, [16..31]=C

    const int tid = threadIdx.x;
    const int g = blockIdx.x * 64 + tid;
    const int bd = g >> 2;
    const int j  = g & 3;
    const int b  = bd >> 11;            // DI=2048
    const int d  = bd & (DI_ - 1);
    const int bL = b * L_;

    float A[4], h[4];
    #pragma unroll
    for (int i = 0; i < 4; ++i) {
        A[i] = -__expf(A_log[d * DS_ + j * 4 + i]);
        h[i] = 0.f;
    }
    const float Dd = Dp[d];

    for (int t0 = 0; t0 < L_; t0 += LCHUNK) {
        __syncthreads();
        for (int e = tid; e < LCHUNK * 32; e += 64) {
            int tt = e >> 5, c = e & 31;
            sBC[tt][c] = dbl[(size_t)(bL + t0 + tt) * 96 + 64 + c];
        }
        __syncthreads();

        #pragma unroll 2
        for (int tt = 0; tt < LCHUNK; ++tt) {
            size_t base = (size_t)(bL + t0 + tt);
            float dtv = xz[base * (2 * DI_) + d];           // dt (overwrote x-half)
            float xv  = xc[base * DI_ + d];
            float zv  = xz[base * (2 * DI_) + DI_ + d];     // z
            float4 Bv = *(const float4*)&sBC[tt][j * 4];
            float4 Cv = *(const float4*)&sBC[tt][16 + j * 4];

            float dtx = dtv * xv;
            float y = 0.f;
            float dA;
            dA = __expf(dtv * A[0]); h[0] = h[0] * dA + dtx * Bv.x; y = fmaf(h[0], Cv.x, y);
            dA = __expf(dtv * A[1]); h[1] = h[1] * dA + dtx * Bv.y; y = fmaf(h[1], Cv.y, y);
            dA = __expf(dtv * A[2]); h[2] = h[2] * dA + dtx * Bv.z; y = fmaf(h[2], Cv.z, y);
            dA = __expf(dtv * A[3]); h[3] = h[3] * dA + dtx * Bv.w; y = fmaf(h[3], Cv.w, y);

            y += __shfl_xor(y, 1);
            y += __shfl_xor(y, 2);

            if (j == 0) {
                float yt = y + xv * Dd;
                float sig = 1.f / (1.f + __expf(-zv));
                xc[base * DI_ + d] = yt * (zv * sig);
            }
        }
    }
}

// ---------------- Launch ----------------
extern "C" void kernel_launch(void* const* d_in, const int* in_sizes, int n_in,
                              void* d_out, int out_size, void* d_ws, size_t ws_size,
                              hipStream_t stream)
{
    const float* u         = (const float*)d_in[0];
    const float* in_proj_w = (const float*)d_in[1];
    const float* conv_w    = (const float*)d_in[2];
    const float* conv_b    = (const float*)d_in[3];
    const float* x_proj_w  = (const float*)d_in[4];
    const float* dt_proj_w = (const float*)d_in[5];
    const float* dt_proj_b = (const float*)d_in[6];
    const float* A_log     = (const float*)d_in[7];
    const float* Dv        = (const float*)d_in[8];
    const float* out_proj_w= (const float*)d_in[9];
    float* out = (float*)d_out;

    // Workspace layout (195 MB peak):
    //   xz : 8192*4096 f32 = 128 MB   (x cols 0..2047 | z cols 2048..4095;
    //                                  after conv, dt GEMM overwrites the x half)
    //   xc : 8192*2048 f32 =  64 MB   (silu(conv(x)); scan overwrites with gated y)
    //   dbl: 8192*96   f32 =   3 MB
    char* ws = (char*)d_ws;
    float* xz  = (float*)(ws);
    float* xc  = (float*)(ws + (size_t)MROWS * 4096 * 4);
    float* dbl = (float*)(ws + (size_t)MROWS * 4096 * 4 + (size_t)MROWS * 2048 * 4);

    // 1) xz = u @ in_proj_w^T           (8192 x 4096, K=1024)
    gemm_bt<0><<<dim3(MROWS / BM, 4096 / BN), 256, 0, stream>>>(
        u, in_proj_w, xz, nullptr, MROWS, 2 * DI_, DM_, DM_, DM_, 2 * DI_);

    // 2) xc = silu(causal_conv(x))      (x = xz[..., :2048])
    conv_silu_kernel<<<(B_ * L_ * DI_) / 256, 256, 0, stream>>>(xz, conv_w, conv_b, xc);

    // 3) dbl = xc @ x_proj_w^T          (8192 x 96, K=2048)
    gemm_bt<0><<<dim3(MROWS / BM, 1), 256, 0, stream>>>(
        xc, x_proj_w, dbl, nullptr, MROWS, DR_ + 2 * DS_, DI_, DI_, DI_, DR_ + 2 * DS_);

    // 4) dt = softplus(dbl[:, :64] @ dt_proj_w^T + dt_proj_b)   (8192 x 2048, K=64)
    //    written into the (now dead) x-half of xz, ldc = 4096
    gemm_bt<1><<<dim3(MROWS / BM, DI_ / BN), 256, 0, stream>>>(
        dbl, dt_proj_w, xz, dt_proj_b, MROWS, DI_, DR_, 96, DR_, 2 * DI_);

    // 5) selective scan + D-skip + z-gate, y written in-place over xc
    scan_kernel<<<(B_ * DI_ * 4) / 64, 64, 0, stream>>>(xc, xz, dbl, A_log, Dv);

    // 6) out = y @ out_proj_w^T         (8192 x 1024, K=2048)
    gemm_bt<0><<<dim3(MROWS / BM, DM_ / BN), 256, 0, stream>>>(
        xc, out_proj_w, out, nullptr, MROWS, DM_, DI_, DI_, DI_, DM_);
}

// Round 3
// 2997.848 us; speedup vs baseline: 1.5025x; 1.5025x over previous
//
#include <hip/hip_runtime.h>
#include <hip/hip_bf16.h>
#include <math.h>

// Problem constants
#define B_   4
#define L_   2048
#define DM_  1024
#define DS_  16
#define DC_  4
#define DI_  2048          // EXP * DM
#define DR_  64            // (DM+15)//16
#define MROWS (B_ * L_)    // 8192

// ---------------- Generic tiled fp32 GEMM:  C[MxN] = A[MxK] * B[NxK]^T ----------------
#define BM 128
#define BN 128
#define BK 16

__device__ inline float softplusf(float x) {
    return (x > 20.f) ? x : log1pf(expf(x));
}

template<int EPI>
__global__ __launch_bounds__(256) void gemm_bt(
    const float* __restrict__ A, const float* __restrict__ B, float* __restrict__ C,
    const float* __restrict__ bias, int M, int N, int K, int lda, int ldb, int ldc)
{
    __shared__ float As[BK][BM + 4];
    __shared__ float Bs[BK][BN + 4];

    const int tid = threadIdx.x;
    const int tx = tid & 15;
    const int ty = tid >> 4;
    const int m0 = blockIdx.x * BM;
    const int n0 = blockIdx.y * BN;

    float acc[8][8];
    #pragma unroll
    for (int i = 0; i < 8; ++i)
        #pragma unroll
        for (int j = 0; j < 8; ++j) acc[i][j] = 0.f;

    for (int k0 = 0; k0 < K; k0 += BK) {
        #pragma unroll
        for (int i = 0; i < 8; ++i) {
            int e = tid + i * 256;
            int mm = e >> 4;
            int kk = e & 15;
            int m = m0 + mm, k = k0 + kk;
            As[kk][mm] = (m < M && k < K) ? A[(size_t)m * lda + k] : 0.f;
            int n = n0 + mm;
            Bs[kk][mm] = (n < N && k < K) ? B[(size_t)n * ldb + k] : 0.f;
        }
        __syncthreads();

        #pragma unroll
        for (int kk = 0; kk < BK; ++kk) {
            float a[8], bb[8];
            #pragma unroll
            for (int i = 0; i < 8; ++i) a[i]  = As[kk][ty * 8 + i];
            #pragma unroll
            for (int j = 0; j < 8; ++j) bb[j] = Bs[kk][tx * 8 + j];
            #pragma unroll
            for (int i = 0; i < 8; ++i)
                #pragma unroll
                for (int j = 0; j < 8; ++j)
                    acc[i][j] = fmaf(a[i], bb[j], acc[i][j]);
        }
        __syncthreads();
    }

    #pragma unroll
    for (int i = 0; i < 8; ++i) {
        int m = m0 + ty * 8 + i;
        if (m >= M) continue;
        #pragma unroll
        for (int j = 0; j < 8; ++j) {
            int n = n0 + tx * 8 + j;
            if (n >= N) continue;
            float v = acc[i][j];
            if (EPI == 1) v = softplusf(v + bias[n]);
            C[(size_t)m * ldc + n] = v;
        }
    }
}

// ---------------- Depthwise causal conv (DC=4) + SiLU ----------------
__global__ __launch_bounds__(256) void conv_silu_kernel(
    const float* __restrict__ xz, const float* __restrict__ cw,
    const float* __restrict__ cb, float* __restrict__ xc)
{
    int idx = blockIdx.x * 256 + threadIdx.x;
    if (idx >= B_ * L_ * DI_) return;
    int d = idx & (DI_ - 1);
    int l = (idx >> 11) & (L_ - 1);
    int b = idx >> 22;

    float acc = cb[d];
    float w0 = cw[d * 4 + 0], w1 = cw[d * 4 + 1], w2 = cw[d * 4 + 2], w3 = cw[d * 4 + 3];
    size_t rowbase = (size_t)(b * L_) * (2 * DI_) + d;
    if (l >= 3) acc += xz[rowbase + (size_t)(l - 3) * (2 * DI_)] * w0;
    if (l >= 2) acc += xz[rowbase + (size_t)(l - 2) * (2 * DI_)] * w1;
    if (l >= 1) acc += xz[rowbase + (size_t)(l - 1) * (2 * DI_)] * w2;
    acc += xz[rowbase + (size_t)l * (2 * DI_)] * w3;

    float sig = 1.f / (1.f + __expf(-acc));
    xc[idx] = acc * sig;
}

// ---------------- Chunked selective scan ----------------
// passA: per (b,d,chunk) local scan from h=0; emits h_out[16], prodA[16]
// combine: per (b,d,n) sequentially folds chunk states, in-place -> h_in
// passC: recompute local scan from h_in; y + D-skip + z-gate over xc
// State layout: [b][chunk][d][n], n fastest (16 floats per (b,c,d))

__global__ __launch_bounds__(256) void scan_passA(
    const float* __restrict__ xz, const float* __restrict__ xc,
    const float* __restrict__ dbl, const float* __restrict__ A_log,
    float* __restrict__ hbuf, float* __restrict__ pbuf, int NC)
{
    __shared__ float sB[128][16];                // max CL = 128
    const int CL = L_ / NC;
    const int d = blockIdx.x * 256 + threadIdx.x;
    const int c = blockIdx.y, b = blockIdx.z;
    const int row0 = b * L_ + c * CL;

    for (int e = threadIdx.x; e < CL * 16; e += 256) {
        int tt = e >> 4, n = e & 15;
        sB[tt][n] = dbl[(size_t)(row0 + tt) * 96 + 64 + n];
    }
    __syncthreads();

    float A[16], h[16];
    #pragma unroll
    for (int i = 0; i < 16; ++i) { A[i] = -__expf(A_log[d * 16 + i]); h[i] = 0.f; }
    float sumdt = 0.f;

    for (int tt = 0; tt < CL; ++tt) {
        size_t base = (size_t)(row0 + tt);
        float dtv = xz[base * 4096 + d];         // dt (x-half of xz)
        float xv  = xc[base * 2048 + d];
        float dtx = dtv * xv;
        sumdt += dtv;
        #pragma unroll
        for (int i = 0; i < 16; ++i) {
            float dA = __expf(dtv * A[i]);
            h[i] = h[i] * dA + dtx * sB[tt][i];
        }
    }

    size_t sidx = (((size_t)b * NC + c) * DI_ + d) * 16;
    #pragma unroll
    for (int i = 0; i < 16; i += 4) {
        *(float4*)&hbuf[sidx + i] = make_float4(h[i], h[i+1], h[i+2], h[i+3]);
        *(float4*)&pbuf[sidx + i] = make_float4(__expf(A[i]   * sumdt), __expf(A[i+1] * sumdt),
                                                __expf(A[i+2] * sumdt), __expf(A[i+3] * sumdt));
    }
}

__global__ __launch_bounds__(256) void scan_combine(
    float* __restrict__ hbuf, const float* __restrict__ pbuf, int NC)
{
    int g = blockIdx.x * 256 + threadIdx.x;      // over B*DI*16 = 131072
    int n = g & 15;
    int d = (g >> 4) & (DI_ - 1);
    int b = g >> 15;
    float hin = 0.f;
    for (int c = 0; c < NC; ++c) {
        size_t idx = (((size_t)b * NC + c) * DI_ + d) * 16 + n;
        float ho = hbuf[idx], p = pbuf[idx];
        hbuf[idx] = hin;
        hin = ho + p * hin;
    }
}

__global__ __launch_bounds__(256) void scan_passC(
    float* __restrict__ xc, const float* __restrict__ xz,
    const float* __restrict__ dbl, const float* __restrict__ A_log,
    const float* __restrict__ hbuf, const float* __restrict__ Dp, int NC)
{
    __shared__ float sBC[128][32];               // max CL = 128 -> 16 KB
    const int CL = L_ / NC;
    const int d = blockIdx.x * 256 + threadIdx.x;
    const int c = blockIdx.y, b = blockIdx.z;
    const int row0 = b * L_ + c * CL;

    for (int e = threadIdx.x; e < CL * 32; e += 256) {
        int tt = e >> 5, k = e & 31;
        sBC[tt][k] = dbl[(size_t)(row0 + tt) * 96 + 64 + k];
    }
    __syncthreads();

    float A[16], h[16];
    size_t sidx = (((size_t)b * NC + c) * DI_ + d) * 16;
    #pragma unroll
    for (int i = 0; i < 16; i += 4) {
        float4 v = *(const float4*)&hbuf[sidx + i];
        h[i] = v.x; h[i+1] = v.y; h[i+2] = v.z; h[i+3] = v.w;
    }
    #pragma unroll
    for (int i = 0; i < 16; ++i) A[i] = -__expf(A_log[d * 16 + i]);
    const float Dd = Dp[d];

    for (int tt = 0; tt < CL; ++tt) {
        size_t base = (size_t)(row0 + tt);
        float dtv = xz[base * 4096 + d];
        float xv  = xc[base * 2048 + d];
        float zv  = xz[base * 4096 + 2048 + d];
        float dtx = dtv * xv;
        float y = 0.f;
        #pragma unroll
        for (int i = 0; i < 16; ++i) {
            float dA = __expf(dtv * A[i]);
            h[i] = h[i] * dA + dtx * sBC[tt][i];
            y = fmaf(h[i], sBC[tt][16 + i], y);
        }
        float yt = y + xv * Dd;
        float sig = 1.f / (1.f + __expf(-zv));
        xc[base * 2048 + d] = yt * (zv * sig);
    }
}

// ---------------- Launch ----------------
extern "C" void kernel_launch(void* const* d_in, const int* in_sizes, int n_in,
                              void* d_out, int out_size, void* d_ws, size_t ws_size,
                              hipStream_t stream)
{
    const float* u         = (const float*)d_in[0];
    const float* in_proj_w = (const float*)d_in[1];
    const float* conv_w    = (const float*)d_in[2];
    const float* conv_b    = (const float*)d_in[3];
    const float* x_proj_w  = (const float*)d_in[4];
    const float* dt_proj_w = (const float*)d_in[5];
    const float* dt_proj_b = (const float*)d_in[6];
    const float* A_log     = (const float*)d_in[7];
    const float* Dv        = (const float*)d_in[8];
    const float* out_proj_w= (const float*)d_in[9];
    float* out = (float*)d_out;

    // Workspace: xz 128MB | xc 64MB | dbl 3MB | hbuf | pbuf
    char* ws = (char*)d_ws;
    float* xz  = (float*)(ws);
    float* xc  = (float*)(ws + (size_t)MROWS * 4096 * 4);
    float* dbl = (float*)(ws + (size_t)MROWS * 4096 * 4 + (size_t)MROWS * 2048 * 4);
    size_t fixed = (size_t)MROWS * 4096 * 4 + (size_t)MROWS * 2048 * 4 + (size_t)MROWS * 96 * 4;

    // Chunk count: prefer NC=32 with states in ws; else NC=16 with states in d_out
    // (d_out is fully overwritten by the final GEMM -> graph/validation safe).
    int NC = 32;
    size_t stateBytes = (size_t)B_ * NC * DI_ * 16 * 4;   // 16.78 MB per buffer
    float *hbuf, *pbuf;
    if (ws_size >= fixed + 2 * stateBytes) {
        hbuf = (float*)(ws + fixed);
        pbuf = (float*)(ws + fixed + stateBytes);
    } else {
        NC = 16;
        stateBytes = (size_t)B_ * NC * DI_ * 16 * 4;      // 8.39 MB per buffer
        hbuf = (float*)d_out;
        pbuf = (float*)((char*)d_out + stateBytes);
    }

    // 1) xz = u @ in_proj_w^T           (8192 x 4096, K=1024)
    gemm_bt<0><<<dim3(MROWS / BM, 4096 / BN), 256, 0, stream>>>(
        u, in_proj_w, xz, nullptr, MROWS, 2 * DI_, DM_, DM_, DM_, 2 * DI_);

    // 2) xc = silu(causal_conv(x))
    conv_silu_kernel<<<(B_ * L_ * DI_) / 256, 256, 0, stream>>>(xz, conv_w, conv_b, xc);

    // 3) dbl = xc @ x_proj_w^T          (8192 x 96, K=2048)
    gemm_bt<0><<<dim3(MROWS / BM, 1), 256, 0, stream>>>(
        xc, x_proj_w, dbl, nullptr, MROWS, DR_ + 2 * DS_, DI_, DI_, DI_, DR_ + 2 * DS_);

    // 4) dt = softplus(dbl[:, :64] @ dt_proj_w^T + dt_proj_b) -> x-half of xz
    gemm_bt<1><<<dim3(MROWS / BM, DI_ / BN), 256, 0, stream>>>(
        dbl, dt_proj_w, xz, dt_proj_b, MROWS, DI_, DR_, 96, DR_, 2 * DI_);

    // 5) chunked scan
    scan_passA<<<dim3(DI_ / 256, NC, B_), 256, 0, stream>>>(xz, xc, dbl, A_log, hbuf, pbuf, NC);
    scan_combine<<<(B_ * DI_ * 16) / 256, 256, 0, stream>>>(hbuf, pbuf, NC);
    scan_passC<<<dim3(DI_ / 256, NC, B_), 256, 0, stream>>>(xc, xz, dbl, A_log, hbuf, Dv, NC);

    // 6) out = y @ out_proj_w^T         (8192 x 1024, K=2048)
    gemm_bt<0><<<dim3(MROWS / BM, DM_ / BN), 256, 0, stream>>>(
        xc, out_proj_w, out, nullptr, MROWS, DM_, DI_, DI_, DI_, DM_);
}

// Round 5
// 1380.728 us; speedup vs baseline: 3.2623x; 2.1712x over previous
//
#include <hip/hip_runtime.h>
#include <hip/hip_bf16.h>
#include <math.h>

// Problem constants
#define B_   4
#define L_   2048
#define DM_  1024
#define DS_  16
#define DI_  2048          // EXP * DM
#define DR_  64            // (DM+15)//16
#define MROWS (B_ * L_)    // 8192

typedef __attribute__((ext_vector_type(8))) short bf16x8;
typedef __attribute__((ext_vector_type(4))) float f32x4;

__device__ inline float softplusf(float x) {
    return (x > 20.f) ? x : log1pf(expf(x));
}

// ---------------- split fp32 -> bf16 hi/lo ----------------
__device__ inline void splitbf(float x, short& h, short& l) {
    unsigned u = __builtin_bit_cast(unsigned, x);
    unsigned r = (u + 0x7FFFu + ((u >> 16) & 1u)) & 0xFFFF0000u;
    h = (short)(r >> 16);
    float lf = x - __builtin_bit_cast(float, r);
    unsigned u2 = __builtin_bit_cast(unsigned, lf);
    unsigned r2 = u2 + 0x7FFFu + ((u2 >> 16) & 1u);
    l = (short)(r2 >> 16);
}

// X:[R][Kin] f32 -> P:[R][3*Kin] bf16.  MODE 0 (A-side): [hi|hi|lo]; MODE 1 (B-side): [hi|lo|hi]
template<int MODE>
__global__ __launch_bounds__(256) void pack_split(
    const float* __restrict__ X, short* __restrict__ P, int R, int Kin)
{
    int idx = blockIdx.x * 256 + threadIdx.x;       // over R*Kin/4
    int kq = Kin >> 2;
    if (idx >= R * kq) return;
    int k4 = (idx % kq) * 4, r = idx / kq;
    float4 v = *(const float4*)&X[(size_t)r * Kin + k4];
    short h0,h1,h2,h3,l0,l1,l2,l3;
    splitbf(v.x,h0,l0); splitbf(v.y,h1,l1); splitbf(v.z,h2,l2); splitbf(v.w,h3,l3);
    short4 hi = make_short4(h0,h1,h2,h3);
    short4 lo = make_short4(l0,l1,l2,l3);
    size_t base = (size_t)r * (3 * Kin) + k4;
    *(short4*)&P[base]            = hi;
    *(short4*)&P[base + Kin]      = (MODE == 0) ? hi : lo;
    *(short4*)&P[base + 2 * Kin]  = (MODE == 0) ? lo : hi;
}

// ---------------- MFMA bf16 GEMM:  C[MxN] = A[MxK] * B[NxK]^T ----------------
// 128x128 tile, 4 waves (2x2), each wave 64x64 = 4x4 frags of 16x16x32.
__device__ inline void gload_lds16(const void* g, void* s) {
    __builtin_amdgcn_global_load_lds(
        (const __attribute__((address_space(1))) void*)g,
        (__attribute__((address_space(3))) void*)s, 16, 0, 0);
}

__global__ __launch_bounds__(256) void gemm_mfma(
    const short* __restrict__ A, const short* __restrict__ B,
    float* __restrict__ C, int M, int N, int K, int ldc)
{
    __shared__ short As[128 * 32];
    __shared__ short Bs[128 * 32];
    const int tid = threadIdx.x;
    const int l  = tid & 63;
    const int wr = (tid >> 6) >> 1, wc = (tid >> 6) & 1;
    const int m0 = blockIdx.x * 128, n0 = blockIdx.y * 128;
    const int lr = l & 15, lk = l >> 4;

    f32x4 acc[4][4];
    #pragma unroll
    for (int mi = 0; mi < 4; ++mi)
        #pragma unroll
        for (int ni = 0; ni < 4; ++ni) acc[mi][ni] = (f32x4){0.f, 0.f, 0.f, 0.f};

    for (int k0 = 0; k0 < K; k0 += 32) {
        #pragma unroll
        for (int i = 0; i < 2; ++i) {
            int e = i * 256 + tid;               // 16B chunk id, 0..511
            int row = e >> 2, cc = (e & 3) * 8;
            int sbase = (i * 256 + (tid & ~63)) * 8;   // wave-uniform LDS base (shorts)
            gload_lds16(&A[(size_t)(m0 + row) * K + k0 + cc], &As[sbase]);
            gload_lds16(&B[(size_t)(n0 + row) * K + k0 + cc], &Bs[sbase]);
        }
        __syncthreads();

        bf16x8 af[4], bfr[4];
        #pragma unroll
        for (int mi = 0; mi < 4; ++mi)
            af[mi] = *(const bf16x8*)&As[(wr * 64 + mi * 16 + lr) * 32 + lk * 8];
        #pragma unroll
        for (int ni = 0; ni < 4; ++ni)
            bfr[ni] = *(const bf16x8*)&Bs[(wc * 64 + ni * 16 + lr) * 32 + lk * 8];
        #pragma unroll
        for (int mi = 0; mi < 4; ++mi)
            #pragma unroll
            for (int ni = 0; ni < 4; ++ni)
                acc[mi][ni] = __builtin_amdgcn_mfma_f32_16x16x32_bf16(
                    af[mi], bfr[ni], acc[mi][ni], 0, 0, 0);
        __syncthreads();
    }

    #pragma unroll
    for (int mi = 0; mi < 4; ++mi)
        #pragma unroll
        for (int ni = 0; ni < 4; ++ni) {
            int col  = n0 + wc * 64 + ni * 16 + lr;
            int rowb = m0 + wr * 64 + mi * 16 + lk * 4;
            #pragma unroll
            for (int j = 0; j < 4; ++j)
                C[(size_t)(rowb + j) * ldc + col] = acc[mi][ni][j];
        }
}

// ---------------- fp32 tiled GEMM (kept for small x_proj / dt GEMMs) ----------------
#define BM 128
#define BN 128
#define BK 16

template<int EPI>
__global__ __launch_bounds__(256) void gemm_bt(
    const float* __restrict__ A, const float* __restrict__ B, float* __restrict__ C,
    const float* __restrict__ bias, int M, int N, int K, int lda, int ldb, int ldc)
{
    __shared__ float As[BK][BM + 4];
    __shared__ float Bs[BK][BN + 4];

    const int tid = threadIdx.x;
    const int tx = tid & 15;
    const int ty = tid >> 4;
    const int m0 = blockIdx.x * BM;
    const int n0 = blockIdx.y * BN;

    float acc[8][8];
    #pragma unroll
    for (int i = 0; i < 8; ++i)
        #pragma unroll
        for (int j = 0; j < 8; ++j) acc[i][j] = 0.f;

    for (int k0 = 0; k0 < K; k0 += BK) {
        #pragma unroll
        for (int i = 0; i < 8; ++i) {
            int e = tid + i * 256;
            int mm = e >> 4;
            int kk = e & 15;
            int m = m0 + mm, k = k0 + kk;
            As[kk][mm] = (m < M && k < K) ? A[(size_t)m * lda + k] : 0.f;
            int n = n0 + mm;
            Bs[kk][mm] = (n < N && k < K) ? B[(size_t)n * ldb + k] : 0.f;
        }
        __syncthreads();

        #pragma unroll
        for (int kk = 0; kk < BK; ++kk) {
            float a[8], bb[8];
            #pragma unroll
            for (int i = 0; i < 8; ++i) a[i]  = As[kk][ty * 8 + i];
            #pragma unroll
            for (int j = 0; j < 8; ++j) bb[j] = Bs[kk][tx * 8 + j];
            #pragma unroll
            for (int i = 0; i < 8; ++i)
                #pragma unroll
                for (int j = 0; j < 8; ++j)
                    acc[i][j] = fmaf(a[i], bb[j], acc[i][j]);
        }
        __syncthreads();
    }

    #pragma unroll
    for (int i = 0; i < 8; ++i) {
        int m = m0 + ty * 8 + i;
        if (m >= M) continue;
        #pragma unroll
        for (int j = 0; j < 8; ++j) {
            int n = n0 + tx * 8 + j;
            if (n >= N) continue;
            float v = acc[i][j];
            if (EPI == 1) v = softplusf(v + bias[n]);
            C[(size_t)m * ldc + n] = v;
        }
    }
}

// ---------------- Depthwise causal conv (DC=4) + SiLU ----------------
__global__ __launch_bounds__(256) void conv_silu_kernel(
    const float* __restrict__ xz, const float* __restrict__ cw,
    const float* __restrict__ cb, float* __restrict__ xc)
{
    int idx = blockIdx.x * 256 + threadIdx.x;
    if (idx >= B_ * L_ * DI_) return;
    int d = idx & (DI_ - 1);
    int l = (idx >> 11) & (L_ - 1);
    int b = idx >> 22;

    float acc = cb[d];
    float w0 = cw[d * 4 + 0], w1 = cw[d * 4 + 1], w2 = cw[d * 4 + 2], w3 = cw[d * 4 + 3];
    size_t rowbase = (size_t)(b * L_) * (2 * DI_) + d;
    if (l >= 3) acc += xz[rowbase + (size_t)(l - 3) * (2 * DI_)] * w0;
    if (l >= 2) acc += xz[rowbase + (size_t)(l - 2) * (2 * DI_)] * w1;
    if (l >= 1) acc += xz[rowbase + (size_t)(l - 1) * (2 * DI_)] * w2;
    acc += xz[rowbase + (size_t)l * (2 * DI_)] * w3;

    float sig = 1.f / (1.f + __expf(-acc));
    xc[idx] = acc * sig;
}

// ---------------- Chunked selective scan ----------------
__global__ __launch_bounds__(256) void scan_passA(
    const float* __restrict__ xz, const float* __restrict__ xc,
    const float* __restrict__ dbl, const float* __restrict__ A_log,
    float* __restrict__ hbuf, float* __restrict__ pbuf, int NC)
{
    __shared__ float sB[128][16];
    const int CL = L_ / NC;
    const int d = blockIdx.x * 256 + threadIdx.x;
    const int c = blockIdx.y, b = blockIdx.z;
    const int row0 = b * L_ + c * CL;

    for (int e = threadIdx.x; e < CL * 16; e += 256) {
        int tt = e >> 4, n = e & 15;
        sB[tt][n] = dbl[(size_t)(row0 + tt) * 96 + 64 + n];
    }
    __syncthreads();

    float A[16], h[16];
    #pragma unroll
    for (int i = 0; i < 16; ++i) { A[i] = -__expf(A_log[d * 16 + i]); h[i] = 0.f; }
    float sumdt = 0.f;

    for (int tt = 0; tt < CL; ++tt) {
        size_t base = (size_t)(row0 + tt);
        float dtv = xz[base * 4096 + d];
        float xv  = xc[base * 2048 + d];
        float dtx = dtv * xv;
        sumdt += dtv;
        #pragma unroll
        for (int i = 0; i < 16; ++i) {
            float dA = __expf(dtv * A[i]);
            h[i] = h[i] * dA + dtx * sB[tt][i];
        }
    }

    size_t sidx = (((size_t)b * NC + c) * DI_ + d) * 16;
    #pragma unroll
    for (int i = 0; i < 16; i += 4) {
        *(float4*)&hbuf[sidx + i] = make_float4(h[i], h[i+1], h[i+2], h[i+3]);
        *(float4*)&pbuf[sidx + i] = make_float4(__expf(A[i]   * sumdt), __expf(A[i+1] * sumdt),
                                                __expf(A[i+2] * sumdt), __expf(A[i+3] * sumdt));
    }
}

__global__ __launch_bounds__(256) void scan_combine(
    float* __restrict__ hbuf, const float* __restrict__ pbuf, int NC)
{
    int g = blockIdx.x * 256 + threadIdx.x;
    int n = g & 15;
    int d = (g >> 4) & (DI_ - 1);
    int b = g >> 15;
    float hin = 0.f;
    for (int c = 0; c < NC; ++c) {
        size_t idx = (((size_t)b * NC + c) * DI_ + d) * 16 + n;
        float ho = hbuf[idx], p = pbuf[idx];
        hbuf[idx] = hin;
        hin = ho + p * hin;
    }
}

__global__ __launch_bounds__(256) void scan_passC(
    float* __restrict__ xc, const float* __restrict__ xz,
    const float* __restrict__ dbl, const float* __restrict__ A_log,
    const float* __restrict__ hbuf, const float* __restrict__ Dp, int NC)
{
    __shared__ float sBC[128][32];
    const int CL = L_ / NC;
    const int d = blockIdx.x * 256 + threadIdx.x;
    const int c = blockIdx.y, b = blockIdx.z;
    const int row0 = b * L_ + c * CL;

    for (int e = threadIdx.x; e < CL * 32; e += 256) {
        int tt = e >> 5, k = e & 31;
        sBC[tt][k] = dbl[(size_t)(row0 + tt) * 96 + 64 + k];
    }
    __syncthreads();

    float A[16], h[16];
    size_t sidx = (((size_t)b * NC + c) * DI_ + d) * 16;
    #pragma unroll
    for (int i = 0; i < 16; i += 4) {
        float4 v = *(const float4*)&hbuf[sidx + i];
        h[i] = v.x; h[i+1] = v.y; h[i+2] = v.z; h[i+3] = v.w;
    }
    #pragma unroll
    for (int i = 0; i < 16; ++i) A[i] = -__expf(A_log[d * 16 + i]);
    const float Dd = Dp[d];

    for (int tt = 0; tt < CL; ++tt) {
        size_t base = (size_t)(row0 + tt);
        float dtv = xz[base * 4096 + d];
        float xv  = xc[base * 2048 + d];
        float zv  = xz[base * 4096 + 2048 + d];
        float dtx = dtv * xv;
        float y = 0.f;
        #pragma unroll
        for (int i = 0; i < 16; ++i) {
            float dA = __expf(dtv * A[i]);
            h[i] = h[i] * dA + dtx * sBC[tt][i];
            y = fmaf(h[i], sBC[tt][16 + i], y);
        }
        float yt = y + xv * Dd;
        float sig = 1.f / (1.f + __expf(-zv));
        xc[base * 2048 + d] = yt * (zv * sig);
    }
}

// ---------------- Launch ----------------
extern "C" void kernel_launch(void* const* d_in, const int* in_sizes, int n_in,
                              void* d_out, int out_size, void* d_ws, size_t ws_size,
                              hipStream_t stream)
{
    const float* u         = (const float*)d_in[0];
    const float* in_proj_w = (const float*)d_in[1];
    const float* conv_w    = (const float*)d_in[2];
    const float* conv_b    = (const float*)d_in[3];
    const float* x_proj_w  = (const float*)d_in[4];
    const float* dt_proj_w = (const float*)d_in[5];
    const float* dt_proj_b = (const float*)d_in[6];
    const float* A_log     = (const float*)d_in[7];
    const float* Dv        = (const float*)d_in[8];
    const float* out_proj_w= (const float*)d_in[9];
    float* out = (float*)d_out;

    const size_t MB = 1024ull * 1024ull;
    char* ws = (char*)d_ws;
    // Layout: [xz 128MB][xc 64MB][dbl 3MB][tail: wP 24MB then hbuf/pbuf 33.5MB]
    float* xz  = (float*)(ws);
    float* xc  = (float*)(ws + 128 * MB);
    float* dbl = (float*)(ws + 192 * MB);
    size_t off_tail = 195 * MB;

    // uP (48MB) borrows xc's slot (dead until conv); yP/owP borrow xz (dead after scan)
    short* uP  = (short*)(ws + 128 * MB);
    short* yP  = (short*)(ws);
    short* owP = (short*)(ws + 96 * MB);

    short* wP;
    if (ws_size >= off_tail + 24 * MB) wP = (short*)(ws + off_tail);
    else                               wP = (short*)d_out;     // fully overwritten later

    int NC = 32;
    size_t stateBytes = (size_t)B_ * NC * DI_ * 16 * 4;        // 16.78 MB
    float *hbuf, *pbuf;
    if (ws_size >= off_tail + 2 * stateBytes) {
        hbuf = (float*)(ws + off_tail);
        pbuf = (float*)(ws + off_tail + stateBytes);
    } else {
        NC = 16;
        stateBytes = (size_t)B_ * NC * DI_ * 16 * 4;           // 8.39 MB
        hbuf = (float*)d_out;
        pbuf = (float*)((char*)d_out + stateBytes);
    }

    // 1) pack u, in_proj_w ; xz = uP @ wP^T  (MFMA, K=3072)
    pack_split<0><<<(MROWS * DM_ / 4 + 255) / 256, 256, 0, stream>>>(u, uP, MROWS, DM_);
    pack_split<1><<<(4096 * DM_ / 4 + 255) / 256, 256, 0, stream>>>(in_proj_w, wP, 2 * DI_, DM_);
    gemm_mfma<<<dim3(MROWS / 128, (2 * DI_) / 128), 256, 0, stream>>>(
        uP, wP, xz, MROWS, 2 * DI_, 3 * DM_, 2 * DI_);

    // 2) xc = silu(causal_conv(x))
    conv_silu_kernel<<<(B_ * L_ * DI_) / 256, 256, 0, stream>>>(xz, conv_w, conv_b, xc);

    // 3) dbl = xc @ x_proj_w^T          (8192 x 96, K=2048)
    gemm_bt<0><<<dim3(MROWS / BM, 1), 256, 0, stream>>>(
        xc, x_proj_w, dbl, nullptr, MROWS, DR_ + 2 * DS_, DI_, DI_, DI_, DR_ + 2 * DS_);

    // 4) dt = softplus(dbl[:, :64] @ dt_proj_w^T + dt_proj_b) -> x-half of xz
    gemm_bt<1><<<dim3(MROWS / BM, DI_ / BN), 256, 0, stream>>>(
        dbl, dt_proj_w, xz, dt_proj_b, MROWS, DI_, DR_, 96, DR_, 2 * DI_);

    // 5) chunked scan
    scan_passA<<<dim3(DI_ / 256, NC, B_), 256, 0, stream>>>(xz, xc, dbl, A_log, hbuf, pbuf, NC);
    scan_combine<<<(B_ * DI_ * 16) / 256, 256, 0, stream>>>(hbuf, pbuf, NC);
    scan_passC<<<dim3(DI_ / 256, NC, B_), 256, 0, stream>>>(xc, xz, dbl, A_log, hbuf, Dv, NC);

    // 6) pack y, out_proj_w ; out = yP @ owP^T  (MFMA, K=6144)
    pack_split<0><<<(MROWS * DI_ / 4 + 255) / 256, 256, 0, stream>>>(xc, yP, MROWS, DI_);
    pack_split<1><<<(DM_ * DI_ / 4 + 255) / 256, 256, 0, stream>>>(out_proj_w, owP, DM_, DI_);
    gemm_mfma<<<dim3(MROWS / 128, DM_ / 128), 256, 0, stream>>>(
        yP, owP, out, MROWS, DM_, 3 * DI_, DM_);
}

// Round 6
// 844.728 us; speedup vs baseline: 5.3324x; 1.6345x over previous
//
#include <hip/hip_runtime.h>
#include <hip/hip_bf16.h>
#include <math.h>

// Problem constants
#define B_   4
#define L_   2048
#define DM_  1024
#define DS_  16
#define DI_  2048          // EXP * DM
#define DR_  64            // (DM+15)//16
#define MROWS (B_ * L_)    // 8192

typedef __attribute__((ext_vector_type(8))) short bf16x8;
typedef __attribute__((ext_vector_type(4))) float f32x4;

__device__ inline float softplusf(float x) {
    return (x > 20.f) ? x : log1pf(expf(x));
}

// ---------------- split fp32 -> bf16 hi/lo (x ~= hi + lo, rel err ~2^-17) ----------------
__device__ inline void splitbf(float x, short& h, short& l) {
    unsigned u = __builtin_bit_cast(unsigned, x);
    unsigned r = (u + 0x7FFFu + ((u >> 16) & 1u)) & 0xFFFF0000u;
    h = (short)(r >> 16);
    float lf = x - __builtin_bit_cast(float, r);
    unsigned u2 = __builtin_bit_cast(unsigned, lf);
    unsigned r2 = u2 + 0x7FFFu + ((u2 >> 16) & 1u);
    l = (short)(r2 >> 16);
}

__device__ inline float bfh2f(unsigned hs) {
    return __builtin_bit_cast(float, hs << 16);
}

// X:[R][Kin] f32 -> H,L:[Ralloc][Kin] bf16, rows >= R zeroed
__global__ __launch_bounds__(256) void pack_hl(
    const float* __restrict__ X, short* __restrict__ H, short* __restrict__ L,
    int R, int Ralloc, int Kin)
{
    int idx = blockIdx.x * 256 + threadIdx.x;       // over Ralloc*Kin/4
    int kq = Kin >> 2;
    if (idx >= Ralloc * kq) return;
    int k4 = (idx % kq) * 4, r = idx / kq;
    short4 hi = make_short4(0,0,0,0), lo = make_short4(0,0,0,0);
    if (r < R) {
        float4 v = *(const float4*)&X[(size_t)r * Kin + k4];
        splitbf(v.x, hi.x, lo.x); splitbf(v.y, hi.y, lo.y);
        splitbf(v.z, hi.z, lo.z); splitbf(v.w, hi.w, lo.w);
    }
    size_t base = (size_t)r * Kin + k4;
    *(short4*)&H[base] = hi;
    *(short4*)&L[base] = lo;
}

// ---------------- MFMA split-bf16 GEMM:  C[MxN] = A[MxK]*B[NxK]^T via HH+HL+LH ----------------
// 128x128 tile, 4 waves (2x2), each wave 64x64 = 4x4 frags of mfma_f32_16x16x32_bf16.
// EPI 0: plain store (ldc). EPI 1: softplus(acc + bias[col]). EPI 2: x_proj special:
//   store col<96 to C (ldc=96), and col<64 also hi/lo-split into dtlH/dtlL [M][64].
__device__ inline void gload_lds16(const void* g, void* s) {
    __builtin_amdgcn_global_load_lds(
        (const __attribute__((address_space(1))) void*)g,
        (__attribute__((address_space(3))) void*)s, 16, 0, 0);
}

template<int EPI>
__global__ __launch_bounds__(256) void gemm3(
    const short* __restrict__ aH, const short* __restrict__ aL,
    const short* __restrict__ bH, const short* __restrict__ bL,
    const float* __restrict__ bias, float* __restrict__ C,
    int M, int N, int K, int ldc,
    short* __restrict__ dtlH, short* __restrict__ dtlL)
{
    __shared__ short As[128 * 32];
    __shared__ short Bs[128 * 32];
    const int tid = threadIdx.x;
    const int l  = tid & 63;
    const int wr = (tid >> 6) >> 1, wc = (tid >> 6) & 1;
    const int m0 = blockIdx.x * 128, n0 = blockIdx.y * 128;
    const int lr = l & 15, lk = l >> 4;

    f32x4 acc[4][4];
    #pragma unroll
    for (int mi = 0; mi < 4; ++mi)
        #pragma unroll
        for (int ni = 0; ni < 4; ++ni) acc[mi][ni] = (f32x4){0.f, 0.f, 0.f, 0.f};

    for (int p = 0; p < 3; ++p) {
        const short* Ap = (p == 2) ? aL : aH;    // products: HH, HL, LH
        const short* Bp = (p == 1) ? bL : bH;
        for (int k0 = 0; k0 < K; k0 += 32) {
            #pragma unroll
            for (int i = 0; i < 2; ++i) {
                int e = i * 256 + tid;               // 16B chunk id, 0..511
                int row = e >> 2, cc = (e & 3) * 8;
                int sbase = (i * 256 + (tid & ~63)) * 8;   // wave-uniform LDS base
                gload_lds16(&Ap[(size_t)(m0 + row) * K + k0 + cc], &As[sbase]);
                gload_lds16(&Bp[(size_t)(n0 + row) * K + k0 + cc], &Bs[sbase]);
            }
            __syncthreads();

            bf16x8 af[4], bfr[4];
            #pragma unroll
            for (int mi = 0; mi < 4; ++mi)
                af[mi] = *(const bf16x8*)&As[(wr * 64 + mi * 16 + lr) * 32 + lk * 8];
            #pragma unroll
            for (int ni = 0; ni < 4; ++ni)
                bfr[ni] = *(const bf16x8*)&Bs[(wc * 64 + ni * 16 + lr) * 32 + lk * 8];
            #pragma unroll
            for (int mi = 0; mi < 4; ++mi)
                #pragma unroll
                for (int ni = 0; ni < 4; ++ni)
                    acc[mi][ni] = __builtin_amdgcn_mfma_f32_16x16x32_bf16(
                        af[mi], bfr[ni], acc[mi][ni], 0, 0, 0);
            __syncthreads();
        }
    }

    #pragma unroll
    for (int mi = 0; mi < 4; ++mi)
        #pragma unroll
        for (int ni = 0; ni < 4; ++ni) {
            int col  = n0 + wc * 64 + ni * 16 + lr;
            int rowb = m0 + wr * 64 + mi * 16 + lk * 4;
            #pragma unroll
            for (int j = 0; j < 4; ++j) {
                float v = acc[mi][ni][j];
                int row = rowb + j;
                if (EPI == 0) {
                    C[(size_t)row * ldc + col] = v;
                } else if (EPI == 1) {
                    C[(size_t)row * ldc + col] = softplusf(v + bias[col]);
                } else {
                    if (col < 96) C[(size_t)row * 96 + col] = v;
                    if (col < 64) {
                        short h, lo2; splitbf(v, h, lo2);
                        dtlH[(size_t)row * 64 + col] = h;
                        dtlL[(size_t)row * 64 + col] = lo2;
                    }
                }
            }
        }
}

// ---------------- Depthwise causal conv (DC=4) + SiLU, output split hi/lo ----------------
// 4 channels per thread; reads x-half of xz (f32), writes xcH/xcL (bf16 split).
__global__ __launch_bounds__(256) void conv_silu_split(
    const float* __restrict__ xz, const float* __restrict__ cw,
    const float* __restrict__ cb, ushort* __restrict__ xcH, ushort* __restrict__ xcL)
{
    int t = blockIdx.x * 256 + threadIdx.x;       // over B*L*DI/4
    if (t >= B_ * L_ * DI_ / 4) return;
    int d4 = (t & (DI_ / 4 - 1)) * 4;             // channel group
    int ll = (t >> 9) & (L_ - 1);
    int b  = t >> 20;

    float4 w0 = *(const float4*)&cw[(d4 + 0) * 4];
    float4 w1 = *(const float4*)&cw[(d4 + 1) * 4];
    float4 w2 = *(const float4*)&cw[(d4 + 2) * 4];
    float4 w3 = *(const float4*)&cw[(d4 + 3) * 4];
    float4 bb = *(const float4*)&cb[d4];
    float a0 = bb.x, a1 = bb.y, a2 = bb.z, a3 = bb.w;

    size_t rb = (size_t)(b * L_) * 4096 + d4;
    if (ll >= 3) { float4 x = *(const float4*)&xz[rb + (size_t)(ll - 3) * 4096];
                   a0 += x.x * w0.x; a1 += x.y * w1.x; a2 += x.z * w2.x; a3 += x.w * w3.x; }
    if (ll >= 2) { float4 x = *(const float4*)&xz[rb + (size_t)(ll - 2) * 4096];
                   a0 += x.x * w0.y; a1 += x.y * w1.y; a2 += x.z * w2.y; a3 += x.w * w3.y; }
    if (ll >= 1) { float4 x = *(const float4*)&xz[rb + (size_t)(ll - 1) * 4096];
                   a0 += x.x * w0.z; a1 += x.y * w1.z; a2 += x.z * w2.z; a3 += x.w * w3.z; }
    {            float4 x = *(const float4*)&xz[rb + (size_t)ll * 4096];
                   a0 += x.x * w0.w; a1 += x.y * w1.w; a2 += x.z * w2.w; a3 += x.w * w3.w; }

    a0 *= 1.f / (1.f + __expf(-a0));
    a1 *= 1.f / (1.f + __expf(-a1));
    a2 *= 1.f / (1.f + __expf(-a2));
    a3 *= 1.f / (1.f + __expf(-a3));

    short4 hi, lo;
    splitbf(a0, hi.x, lo.x); splitbf(a1, hi.y, lo.y);
    splitbf(a2, hi.z, lo.z); splitbf(a3, hi.w, lo.w);
    size_t oidx = (size_t)(b * L_ + ll) * DI_ + d4;
    *(short4*)&xcH[oidx] = hi;
    *(short4*)&xcL[oidx] = lo;
}

// ---------------- Chunked selective scan ----------------
__global__ __launch_bounds__(256) void scan_passA(
    const float* __restrict__ xz, const ushort* __restrict__ xcH, const ushort* __restrict__ xcL,
    const float* __restrict__ dbl, const float* __restrict__ A_log,
    float* __restrict__ hbuf, float* __restrict__ pbuf, int NC)
{
    __shared__ float sB[128][16];
    const int CL = L_ / NC;
    const int d = blockIdx.x * 256 + threadIdx.x;
    const int c = blockIdx.y, b = blockIdx.z;
    const int row0 = b * L_ + c * CL;

    for (int e = threadIdx.x; e < CL * 16; e += 256) {
        int tt = e >> 4, n = e & 15;
        sB[tt][n] = dbl[(size_t)(row0 + tt) * 96 + 64 + n];
    }
    __syncthreads();

    float A[16], h[16];
    #pragma unroll
    for (int i = 0; i < 16; ++i) { A[i] = -__expf(A_log[d * 16 + i]); h[i] = 0.f; }
    float sumdt = 0.f;

    for (int tt = 0; tt < CL; ++tt) {
        size_t base = (size_t)(row0 + tt);
        float dtv = xz[base * 4096 + d];
        float xv  = bfh2f(xcH[base * 2048 + d]) + bfh2f(xcL[base * 2048 + d]);
        float dtx = dtv * xv;
        sumdt += dtv;
        #pragma unroll
        for (int i = 0; i < 16; ++i) {
            float dA = __expf(dtv * A[i]);
            h[i] = h[i] * dA + dtx * sB[tt][i];
        }
    }

    size_t sidx = (((size_t)b * NC + c) * DI_ + d) * 16;
    #pragma unroll
    for (int i = 0; i < 16; i += 4) {
        *(float4*)&hbuf[sidx + i] = make_float4(h[i], h[i+1], h[i+2], h[i+3]);
        *(float4*)&pbuf[sidx + i] = make_float4(__expf(A[i]   * sumdt), __expf(A[i+1] * sumdt),
                                                __expf(A[i+2] * sumdt), __expf(A[i+3] * sumdt));
    }
}

__global__ __launch_bounds__(256) void scan_combine(
    float* __restrict__ hbuf, const float* __restrict__ pbuf, int NC)
{
    int g = blockIdx.x * 256 + threadIdx.x;
    int n = g & 15;
    int d = (g >> 4) & (DI_ - 1);
    int b = g >> 15;
    float hin = 0.f;
    for (int c = 0; c < NC; ++c) {
        size_t idx = (((size_t)b * NC + c) * DI_ + d) * 16 + n;
        float ho = hbuf[idx], p = pbuf[idx];
        hbuf[idx] = hin;
        hin = ho + p * hin;
    }
}

__global__ __launch_bounds__(256) void scan_passC(
    ushort* __restrict__ xcH, ushort* __restrict__ xcL, const float* __restrict__ xz,
    const float* __restrict__ dbl, const float* __restrict__ A_log,
    const float* __restrict__ hbuf, const float* __restrict__ Dp, int NC)
{
    __shared__ float sBC[128][32];
    const int CL = L_ / NC;
    const int d = blockIdx.x * 256 + threadIdx.x;
    const int c = blockIdx.y, b = blockIdx.z;
    const int row0 = b * L_ + c * CL;

    for (int e = threadIdx.x; e < CL * 32; e += 256) {
        int tt = e >> 5, k = e & 31;
        sBC[tt][k] = dbl[(size_t)(row0 + tt) * 96 + 64 + k];
    }
    __syncthreads();

    float A[16], h[16];
    size_t sidx = (((size_t)b * NC + c) * DI_ + d) * 16;
    #pragma unroll
    for (int i = 0; i < 16; i += 4) {
        float4 v = *(const float4*)&hbuf[sidx + i];
        h[i] = v.x; h[i+1] = v.y; h[i+2] = v.z; h[i+3] = v.w;
    }
    #pragma unroll
    for (int i = 0; i < 16; ++i) A[i] = -__expf(A_log[d * 16 + i]);
    const float Dd = Dp[d];

    for (int tt = 0; tt < CL; ++tt) {
        size_t base = (size_t)(row0 + tt);
        float dtv = xz[base * 4096 + d];
        float xv  = bfh2f(xcH[base * 2048 + d]) + bfh2f(xcL[base * 2048 + d]);
        float zv  = xz[base * 4096 + 2048 + d];
        float dtx = dtv * xv;
        float y = 0.f;
        #pragma unroll
        for (int i = 0; i < 16; ++i) {
            float dA = __expf(dtv * A[i]);
            h[i] = h[i] * dA + dtx * sBC[tt][i];
            y = fmaf(h[i], sBC[tt][16 + i], y);
        }
        float yt = y + xv * Dd;
        float sig = 1.f / (1.f + __expf(-zv));
        float ov = yt * (zv * sig);
        short hh, lo; splitbf(ov, hh, lo);
        xcH[base * 2048 + d] = (ushort)hh;
        xcL[base * 2048 + d] = (ushort)lo;
    }
}

// ---------------- Launch ----------------
extern "C" void kernel_launch(void* const* d_in, const int* in_sizes, int n_in,
                              void* d_out, int out_size, void* d_ws, size_t ws_size,
                              hipStream_t stream)
{
    const float* u         = (const float*)d_in[0];
    const float* in_proj_w = (const float*)d_in[1];
    const float* conv_w    = (const float*)d_in[2];
    const float* conv_b    = (const float*)d_in[3];
    const float* x_proj_w  = (const float*)d_in[4];
    const float* dt_proj_w = (const float*)d_in[5];
    const float* dt_proj_b = (const float*)d_in[6];
    const float* A_log     = (const float*)d_in[7];
    const float* Dv        = (const float*)d_in[8];
    const float* out_proj_w= (const float*)d_in[9];
    float* out = (float*)d_out;

    const size_t MB = 1024ull * 1024ull;
    char* ws = (char*)d_ws;
    // ws (195 MiB total, proven safe):
    //   xz   [8192][4096] f32 @0      (128 MiB)  x|z; dt overwrites x-half after conv
    //   xcH  [8192][2048] bf16 @128MB ( 32 MiB)  \ conv out hi/lo; scan rewrites with y hi/lo
    //   xcL  [8192][2048] bf16 @160MB ( 32 MiB)  /
    //   dblP [8192][96]   f32 @192MB (  3 MiB)
    // Aliases: uH/uL/wiH/wiL in the xc region (dead until conv);
    //          opH/opL in xz (dead after scan).
    float*  xz   = (float*)(ws);
    ushort* xcH  = (ushort*)(ws + 128 * MB);
    ushort* xcL  = (ushort*)(ws + 160 * MB);
    float*  dblP = (float*)(ws + 192 * MB);
    short*  uH   = (short*)(ws + 128 * MB);           // 16 MiB
    short*  uL   = (short*)(ws + 144 * MB);           // 16 MiB
    short*  wiH  = (short*)(ws + 160 * MB);           //  8 MiB
    short*  wiL  = (short*)(ws + 168 * MB);           //  8 MiB
    short*  opH  = (short*)(ws);                      //  4 MiB (post-scan)
    short*  opL  = (short*)(ws + 4 * MB);             //  4 MiB

    // d_out (32 MiB) as scratch until final GEMM overwrites it all:
    char* doc = (char*)d_out;
    float* hbuf = (float*)(doc);                      // 8 MiB (NC=16)
    float* pbuf = (float*)(doc + 8 * MB);             // 8 MiB
    short* xpH  = (short*)(doc + 16 * MB);            // 512 KiB ([128][2048], rows 96+ zero)
    short* xpL  = (short*)(doc + 16 * MB + 512 * 1024);
    short* dtwH = (short*)(doc + 17 * MB);            // 256 KiB ([2048][64])
    short* dtwL = (short*)(doc + 17 * MB + 256 * 1024);
    short* dtlH = (short*)(doc + 18 * MB);            // 1 MiB ([8192][64])
    short* dtlL = (short*)(doc + 19 * MB);
    const int NC = 16;

    // 1) pack u + in_proj_w; xz = u @ in_proj_w^T  (M=8192, N=4096, K=1024)
    pack_hl<<<(MROWS * DM_ / 4 + 255) / 256, 256, 0, stream>>>(u, uH, uL, MROWS, MROWS, DM_);
    pack_hl<<<(4096 * DM_ / 4 + 255) / 256, 256, 0, stream>>>(in_proj_w, wiH, wiL, 4096, 4096, DM_);
    gemm3<0><<<dim3(64, 32), 256, 0, stream>>>(
        uH, uL, wiH, wiL, nullptr, xz, MROWS, 2 * DI_, DM_, 2 * DI_, nullptr, nullptr);

    // 2) conv + silu -> xcH/xcL (split)
    conv_silu_split<<<(B_ * L_ * DI_ / 4 + 255) / 256, 256, 0, stream>>>(
        xz, conv_w, conv_b, xcH, xcL);

    // 3) x_proj: dblP = xc @ x_proj_w^T (N pad 128), epilogue also splits cols<64 -> dtlH/L
    pack_hl<<<(128 * DI_ / 4 + 255) / 256, 256, 0, stream>>>(x_proj_w, xpH, xpL, 96, 128, DI_);
    gemm3<2><<<dim3(64, 1), 256, 0, stream>>>(
        (const short*)xcH, (const short*)xcL, xpH, xpL, nullptr, dblP,
        MROWS, 128, DI_, 96, dtlH, dtlL);

    // 4) dt = softplus(dtl @ dt_proj_w^T + b) -> x-half of xz (ldc=4096)
    pack_hl<<<(DI_ * DR_ / 4 + 255) / 256, 256, 0, stream>>>(dt_proj_w, dtwH, dtwL, DI_, DI_, DR_);
    gemm3<1><<<dim3(64, 16), 256, 0, stream>>>(
        dtlH, dtlL, dtwH, dtwL, dt_proj_b, xz, MROWS, DI_, DR_, 2 * DI_, nullptr, nullptr);

    // 5) chunked scan; y (gated) written back into xcH/xcL as hi/lo
    scan_passA<<<dim3(DI_ / 256, NC, B_), 256, 0, stream>>>(xz, xcH, xcL, dblP, A_log, hbuf, pbuf, NC);
    scan_combine<<<(B_ * DI_ * 16) / 256, 256, 0, stream>>>(hbuf, pbuf, NC);
    scan_passC<<<dim3(DI_ / 256, NC, B_), 256, 0, stream>>>(xcH, xcL, xz, dblP, A_log, hbuf, Dv, NC);

    // 6) out = y @ out_proj_w^T  (M=8192, N=1024, K=2048); op weights packed into dead xz
    pack_hl<<<(DM_ * DI_ / 4 + 255) / 256, 256, 0, stream>>>(out_proj_w, opH, opL, DM_, DM_, DI_);
    gemm3<0><<<dim3(64, 8), 256, 0, stream>>>(
        (const short*)xcH, (const short*)xcL, opH, opL, nullptr, out,
        MROWS, DM_, DI_, DM_, nullptr, nullptr);
}

// Round 7
// 736.729 us; speedup vs baseline: 6.1140x; 1.1466x over previous
//
#include <hip/hip_runtime.h>
#include <hip/hip_bf16.h>
#include <math.h>

// Problem constants
#define B_   4
#define L_   2048
#define DM_  1024
#define DS_  16
#define DI_  2048          // EXP * DM
#define DR_  64            // (DM+15)//16
#define MROWS (B_ * L_)    // 8192

typedef __attribute__((ext_vector_type(8))) short bf16x8;
typedef __attribute__((ext_vector_type(4))) float f32x4;

__device__ inline float softplusf(float x) {
    return (x > 20.f) ? x : log1pf(expf(x));
}

// ---------------- split fp32 -> bf16 hi/lo (x ~= hi + lo, rel err ~2^-17) ----------------
__device__ inline void splitbf(float x, short& h, short& l) {
    unsigned u = __builtin_bit_cast(unsigned, x);
    unsigned r = (u + 0x7FFFu + ((u >> 16) & 1u)) & 0xFFFF0000u;
    h = (short)(r >> 16);
    float lf = x - __builtin_bit_cast(float, r);
    unsigned u2 = __builtin_bit_cast(unsigned, lf);
    unsigned r2 = u2 + 0x7FFFu + ((u2 >> 16) & 1u);
    l = (short)(r2 >> 16);
}

__device__ inline float bfh2f(unsigned hs) {
    return __builtin_bit_cast(float, hs << 16);
}

// X:[R][Kin] f32 -> H,L:[Ralloc][Kin] bf16, rows >= R zeroed
__global__ __launch_bounds__(256) void pack_hl(
    const float* __restrict__ X, short* __restrict__ H, short* __restrict__ L,
    int R, int Ralloc, int Kin)
{
    int idx = blockIdx.x * 256 + threadIdx.x;       // over Ralloc*Kin/4
    int kq = Kin >> 2;
    if (idx >= Ralloc * kq) return;
    int k4 = (idx % kq) * 4, r = idx / kq;
    short4 hi = make_short4(0,0,0,0), lo = make_short4(0,0,0,0);
    if (r < R) {
        float4 v = *(const float4*)&X[(size_t)r * Kin + k4];
        splitbf(v.x, hi.x, lo.x); splitbf(v.y, hi.y, lo.y);
        splitbf(v.z, hi.z, lo.z); splitbf(v.w, hi.w, lo.w);
    }
    size_t base = (size_t)r * Kin + k4;
    *(short4*)&H[base] = hi;
    *(short4*)&L[base] = lo;
}

// ---------------- Fused MFMA split-bf16 GEMM: C = A*B^T via HH+HL+LH, ONE K-sweep ----------------
// 128x128 tile, 4 waves (2x2), 48 MFMA per barrier pair (4 LDS tiles: aH,aL,bH,bL).
// Grid: x = flattened (mblocks * nblocks), XCD-swizzled; y = K-chunk (kOff = y*kLen).
// EPI 0: plain store. EPI 1: softplus(acc + bias[col]). EPI 3: split-K partial, C + y*M*ldc.
__device__ inline void gload_lds16(const void* g, void* s) {
    __builtin_amdgcn_global_load_lds(
        (const __attribute__((address_space(1))) void*)g,
        (__attribute__((address_space(3))) void*)s, 16, 0, 0);
}

template<int EPI>
__global__ __launch_bounds__(256) void gemm3(
    const short* __restrict__ aH, const short* __restrict__ aL,
    const short* __restrict__ bH, const short* __restrict__ bL,
    const float* __restrict__ bias, float* __restrict__ C,
    int mblocks, int lda, int kLen, int ldc, int M)
{
    __shared__ short AsH[128 * 32];
    __shared__ short AsL[128 * 32];
    __shared__ short BsH[128 * 32];
    __shared__ short BsL[128 * 32];

    const int tid = threadIdx.x;
    const int l  = tid & 63;
    const int wr = (tid >> 6) >> 1, wc = (tid >> 6) & 1;
    const int lr = l & 15, lk = l >> 4;

    // XCD-aware bijective swizzle (all our grids are multiples of 8)
    int nwg = gridDim.x;
    int bid = blockIdx.x;
    if ((nwg & 7) == 0) { int cpx = nwg >> 3; bid = (bid & 7) * cpx + (bid >> 3); }
    const int m0 = (bid % mblocks) * 128;
    const int n0 = (bid / mblocks) * 128;
    const int kOff = blockIdx.y * kLen;

    f32x4 acc[4][4];
    #pragma unroll
    for (int mi = 0; mi < 4; ++mi)
        #pragma unroll
        for (int ni = 0; ni < 4; ++ni) acc[mi][ni] = (f32x4){0.f, 0.f, 0.f, 0.f};

    for (int k0 = 0; k0 < kLen; k0 += 32) {
        int kk = kOff + k0;
        #pragma unroll
        for (int i = 0; i < 2; ++i) {
            int e = i * 256 + tid;               // 16B chunk id, 0..511
            int row = e >> 2, cc = (e & 3) * 8;
            int sbase = (i * 256 + (tid & ~63)) * 8;   // wave-uniform LDS base (shorts)
            size_t offA = (size_t)(m0 + row) * lda + kk + cc;
            size_t offB = (size_t)(n0 + row) * lda + kk + cc;
            gload_lds16(&aH[offA], &AsH[sbase]);
            gload_lds16(&aL[offA], &AsL[sbase]);
            gload_lds16(&bH[offB], &BsH[sbase]);
            gload_lds16(&bL[offB], &BsL[sbase]);
        }
        __syncthreads();

        bf16x8 bfh[4], bfl[4];
        #pragma unroll
        for (int ni = 0; ni < 4; ++ni) {
            int boff = (wc * 64 + ni * 16 + lr) * 32 + lk * 8;
            bfh[ni] = *(const bf16x8*)&BsH[boff];
            bfl[ni] = *(const bf16x8*)&BsL[boff];
        }
        #pragma unroll
        for (int mi = 0; mi < 4; ++mi) {
            int aoff = (wr * 64 + mi * 16 + lr) * 32 + lk * 8;
            bf16x8 ah = *(const bf16x8*)&AsH[aoff];
            bf16x8 al = *(const bf16x8*)&AsL[aoff];
            #pragma unroll
            for (int ni = 0; ni < 4; ++ni) {
                acc[mi][ni] = __builtin_amdgcn_mfma_f32_16x16x32_bf16(ah, bfh[ni], acc[mi][ni], 0, 0, 0);
                acc[mi][ni] = __builtin_amdgcn_mfma_f32_16x16x32_bf16(ah, bfl[ni], acc[mi][ni], 0, 0, 0);
                acc[mi][ni] = __builtin_amdgcn_mfma_f32_16x16x32_bf16(al, bfh[ni], acc[mi][ni], 0, 0, 0);
            }
        }
        __syncthreads();
    }

    float* Cp = C;
    if (EPI == 3) Cp = C + (size_t)blockIdx.y * M * ldc;

    #pragma unroll
    for (int mi = 0; mi < 4; ++mi)
        #pragma unroll
        for (int ni = 0; ni < 4; ++ni) {
            int col  = n0 + wc * 64 + ni * 16 + lr;
            int rowb = m0 + wr * 64 + mi * 16 + lk * 4;
            #pragma unroll
            for (int j = 0; j < 4; ++j) {
                float v = acc[mi][ni][j];
                int row = rowb + j;
                if (EPI == 1) v = softplusf(v + bias[col]);
                Cp[(size_t)row * ldc + col] = v;
            }
        }
}

// ---------------- x_proj split-K reduce: sum 4 partials; dblP + dt-input split ----------------
__global__ __launch_bounds__(256) void xproj_reduce(
    const float* __restrict__ part, float* __restrict__ dblP,
    short* __restrict__ dtlH, short* __restrict__ dtlL)
{
    int idx = blockIdx.x * 256 + threadIdx.x;        // over MROWS*128
    if (idx >= MROWS * 128) return;
    int col = idx & 127, row = idx >> 7;
    const size_t S = (size_t)MROWS * 128;
    float s = part[idx] + part[idx + S] + part[idx + 2 * S] + part[idx + 3 * S];
    if (col < 96) dblP[(size_t)row * 96 + col] = s;
    if (col < 64) {
        short h, lo; splitbf(s, h, lo);
        dtlH[(size_t)row * 64 + col] = h;
        dtlL[(size_t)row * 64 + col] = lo;
    }
}

// ---------------- Depthwise causal conv (DC=4) + SiLU, output split hi/lo ----------------
__global__ __launch_bounds__(256) void conv_silu_split(
    const float* __restrict__ xz, const float* __restrict__ cw,
    const float* __restrict__ cb, ushort* __restrict__ xcH, ushort* __restrict__ xcL)
{
    int t = blockIdx.x * 256 + threadIdx.x;       // over B*L*DI/4
    if (t >= B_ * L_ * DI_ / 4) return;
    int d4 = (t & (DI_ / 4 - 1)) * 4;             // channel group
    int ll = (t >> 9) & (L_ - 1);
    int b  = t >> 20;

    float4 w0 = *(const float4*)&cw[(d4 + 0) * 4];
    float4 w1 = *(const float4*)&cw[(d4 + 1) * 4];
    float4 w2 = *(const float4*)&cw[(d4 + 2) * 4];
    float4 w3 = *(const float4*)&cw[(d4 + 3) * 4];
    float4 bb = *(const float4*)&cb[d4];
    float a0 = bb.x, a1 = bb.y, a2 = bb.z, a3 = bb.w;

    size_t rb = (size_t)(b * L_) * 4096 + d4;
    if (ll >= 3) { float4 x = *(const float4*)&xz[rb + (size_t)(ll - 3) * 4096];
                   a0 += x.x * w0.x; a1 += x.y * w1.x; a2 += x.z * w2.x; a3 += x.w * w3.x; }
    if (ll >= 2) { float4 x = *(const float4*)&xz[rb + (size_t)(ll - 2) * 4096];
                   a0 += x.x * w0.y; a1 += x.y * w1.y; a2 += x.z * w2.y; a3 += x.w * w3.y; }
    if (ll >= 1) { float4 x = *(const float4*)&xz[rb + (size_t)(ll - 1) * 4096];
                   a0 += x.x * w0.z; a1 += x.y * w1.z; a2 += x.z * w2.z; a3 += x.w * w3.z; }
    {            float4 x = *(const float4*)&xz[rb + (size_t)ll * 4096];
                   a0 += x.x * w0.w; a1 += x.y * w1.w; a2 += x.z * w2.w; a3 += x.w * w3.w; }

    a0 *= 1.f / (1.f + __expf(-a0));
    a1 *= 1.f / (1.f + __expf(-a1));
    a2 *= 1.f / (1.f + __expf(-a2));
    a3 *= 1.f / (1.f + __expf(-a3));

    short4 hi, lo;
    splitbf(a0, hi.x, lo.x); splitbf(a1, hi.y, lo.y);
    splitbf(a2, hi.z, lo.z); splitbf(a3, hi.w, lo.w);
    size_t oidx = (size_t)(b * L_ + ll) * DI_ + d4;
    *(short4*)&xcH[oidx] = hi;
    *(short4*)&xcL[oidx] = lo;
}

// ---------------- Chunked selective scan ----------------
__global__ __launch_bounds__(256) void scan_passA(
    const float* __restrict__ xz, const ushort* __restrict__ xcH, const ushort* __restrict__ xcL,
    const float* __restrict__ dbl, const float* __restrict__ A_log,
    float* __restrict__ hbuf, float* __restrict__ pbuf, int NC)
{
    __shared__ float sB[128][16];
    const int CL = L_ / NC;
    const int d = blockIdx.x * 256 + threadIdx.x;
    const int c = blockIdx.y, b = blockIdx.z;
    const int row0 = b * L_ + c * CL;

    for (int e = threadIdx.x; e < CL * 16; e += 256) {
        int tt = e >> 4, n = e & 15;
        sB[tt][n] = dbl[(size_t)(row0 + tt) * 96 + 64 + n];
    }
    __syncthreads();

    float A[16], h[16];
    #pragma unroll
    for (int i = 0; i < 16; ++i) { A[i] = -__expf(A_log[d * 16 + i]); h[i] = 0.f; }
    float sumdt = 0.f;

    for (int tt = 0; tt < CL; ++tt) {
        size_t base = (size_t)(row0 + tt);
        float dtv = xz[base * 4096 + d];
        float xv  = bfh2f(xcH[base * 2048 + d]) + bfh2f(xcL[base * 2048 + d]);
        float dtx = dtv * xv;
        sumdt += dtv;
        #pragma unroll
        for (int i = 0; i < 16; ++i) {
            float dA = __expf(dtv * A[i]);
            h[i] = h[i] * dA + dtx * sB[tt][i];
        }
    }

    size_t sidx = (((size_t)b * NC + c) * DI_ + d) * 16;
    #pragma unroll
    for (int i = 0; i < 16; i += 4) {
        *(float4*)&hbuf[sidx + i] = make_float4(h[i], h[i+1], h[i+2], h[i+3]);
        *(float4*)&pbuf[sidx + i] = make_float4(__expf(A[i]   * sumdt), __expf(A[i+1] * sumdt),
                                                __expf(A[i+2] * sumdt), __expf(A[i+3] * sumdt));
    }
}

__global__ __launch_bounds__(256) void scan_combine(
    float* __restrict__ hbuf, const float* __restrict__ pbuf, int NC)
{
    int g = blockIdx.x * 256 + threadIdx.x;
    int n = g & 15;
    int d = (g >> 4) & (DI_ - 1);
    int b = g >> 15;
    float hin = 0.f;
    for (int c = 0; c < NC; ++c) {
        size_t idx = (((size_t)b * NC + c) * DI_ + d) * 16 + n;
        float ho = hbuf[idx], p = pbuf[idx];
        hbuf[idx] = hin;
        hin = ho + p * hin;
    }
}

__global__ __launch_bounds__(256) void scan_passC(
    ushort* __restrict__ xcH, ushort* __restrict__ xcL, const float* __restrict__ xz,
    const float* __restrict__ dbl, const float* __restrict__ A_log,
    const float* __restrict__ hbuf, const float* __restrict__ Dp, int NC)
{
    __shared__ float sBC[128][32];
    const int CL = L_ / NC;
    const int d = blockIdx.x * 256 + threadIdx.x;
    const int c = blockIdx.y, b = blockIdx.z;
    const int row0 = b * L_ + c * CL;

    for (int e = threadIdx.x; e < CL * 32; e += 256) {
        int tt = e >> 5, k = e & 31;
        sBC[tt][k] = dbl[(size_t)(row0 + tt) * 96 + 64 + k];
    }
    __syncthreads();

    float A[16], h[16];
    size_t sidx = (((size_t)b * NC + c) * DI_ + d) * 16;
    #pragma unroll
    for (int i = 0; i < 16; i += 4) {
        float4 v = *(const float4*)&hbuf[sidx + i];
        h[i] = v.x; h[i+1] = v.y; h[i+2] = v.z; h[i+3] = v.w;
    }
    #pragma unroll
    for (int i = 0; i < 16; ++i) A[i] = -__expf(A_log[d * 16 + i]);
    const float Dd = Dp[d];

    for (int tt = 0; tt < CL; ++tt) {
        size_t base = (size_t)(row0 + tt);
        float dtv = xz[base * 4096 + d];
        float xv  = bfh2f(xcH[base * 2048 + d]) + bfh2f(xcL[base * 2048 + d]);
        float zv  = xz[base * 4096 + 2048 + d];
        float dtx = dtv * xv;
        float y = 0.f;
        #pragma unroll
        for (int i = 0; i < 16; ++i) {
            float dA = __expf(dtv * A[i]);
            h[i] = h[i] * dA + dtx * sBC[tt][i];
            y = fmaf(h[i], sBC[tt][16 + i], y);
        }
        float yt = y + xv * Dd;
        float sig = 1.f / (1.f + __expf(-zv));
        float ov = yt * (zv * sig);
        short hh, lo; splitbf(ov, hh, lo);
        xcH[base * 2048 + d] = (ushort)hh;
        xcL[base * 2048 + d] = (ushort)lo;
    }
}

// ---------------- Launch ----------------
extern "C" void kernel_launch(void* const* d_in, const int* in_sizes, int n_in,
                              void* d_out, int out_size, void* d_ws, size_t ws_size,
                              hipStream_t stream)
{
    const float* u         = (const float*)d_in[0];
    const float* in_proj_w = (const float*)d_in[1];
    const float* conv_w    = (const float*)d_in[2];
    const float* conv_b    = (const float*)d_in[3];
    const float* x_proj_w  = (const float*)d_in[4];
    const float* dt_proj_w = (const float*)d_in[5];
    const float* dt_proj_b = (const float*)d_in[6];
    const float* A_log     = (const float*)d_in[7];
    const float* Dv        = (const float*)d_in[8];
    const float* out_proj_w= (const float*)d_in[9];
    float* out = (float*)d_out;

    const size_t MB = 1024ull * 1024ull;
    char* ws = (char*)d_ws;
    // ws (195 MiB, proven): xz f32 @0 (128M) | xcH bf16 @128M (32M) | xcL @160M (32M) | dblP @192M (3M)
    // Aliases: uH/uL/wiH/wiL in xc region (dead until conv); opH/opL in xz (dead after scan).
    float*  xz   = (float*)(ws);
    ushort* xcH  = (ushort*)(ws + 128 * MB);
    ushort* xcL  = (ushort*)(ws + 160 * MB);
    float*  dblP = (float*)(ws + 192 * MB);
    short*  uH   = (short*)(ws + 128 * MB);           // 16 MiB
    short*  uL   = (short*)(ws + 144 * MB);           // 16 MiB
    short*  wiH  = (short*)(ws + 160 * MB);           //  8 MiB
    short*  wiL  = (short*)(ws + 168 * MB);           //  8 MiB
    short*  opH  = (short*)(ws);                      //  4 MiB (post-scan)
    short*  opL  = (short*)(ws + 4 * MB);             //  4 MiB

    // d_out (32 MiB) as scratch until the final GEMM overwrites it all:
    //   xpart [4][8192][128] f32 @0..16M (x_proj partials; dead after reduce)
    //   hbuf @0 (8M), pbuf @8M (scan; written after reduce)
    //   xpH/xpL @16M (1M), dtwH/dtwL @17M (0.5M), dtlH/dtlL @18M,19M (2M)
    char* doc = (char*)d_out;
    float* xpart = (float*)(doc);
    float* hbuf = (float*)(doc);
    float* pbuf = (float*)(doc + 8 * MB);
    short* xpH  = (short*)(doc + 16 * MB);
    short* xpL  = (short*)(doc + 16 * MB + 512 * 1024);
    short* dtwH = (short*)(doc + 17 * MB);
    short* dtwL = (short*)(doc + 17 * MB + 256 * 1024);
    short* dtlH = (short*)(doc + 18 * MB);
    short* dtlL = (short*)(doc + 19 * MB);
    const int NC = 16;

    // 1) pack u + in_proj_w; xz = u @ in_proj_w^T  (M=8192, N=4096, K=1024)
    pack_hl<<<(MROWS * DM_ / 4 + 255) / 256, 256, 0, stream>>>(u, uH, uL, MROWS, MROWS, DM_);
    pack_hl<<<(4096 * DM_ / 4 + 255) / 256, 256, 0, stream>>>(in_proj_w, wiH, wiL, 4096, 4096, DM_);
    gemm3<0><<<dim3(2048, 1), 256, 0, stream>>>(
        uH, uL, wiH, wiL, nullptr, xz, 64, DM_, DM_, 2 * DI_, MROWS);

    // 2) conv + silu -> xcH/xcL (split)
    conv_silu_split<<<(B_ * L_ * DI_ / 4 + 255) / 256, 256, 0, stream>>>(
        xz, conv_w, conv_b, xcH, xcL);

    // 3) x_proj: split-K=4 partials -> reduce (writes dblP + dt-input split)
    pack_hl<<<(128 * DI_ / 4 + 255) / 256, 256, 0, stream>>>(x_proj_w, xpH, xpL, 96, 128, DI_);
    gemm3<3><<<dim3(64, 4), 256, 0, stream>>>(
        (const short*)xcH, (const short*)xcL, xpH, xpL, nullptr, xpart, 64, DI_, DI_ / 4, 128, MROWS);
    xproj_reduce<<<(MROWS * 128) / 256, 256, 0, stream>>>(xpart, dblP, dtlH, dtlL);

    // 4) dt = softplus(dtl @ dt_proj_w^T + b) -> x-half of xz (ldc=4096)
    pack_hl<<<(DI_ * DR_ / 4 + 255) / 256, 256, 0, stream>>>(dt_proj_w, dtwH, dtwL, DI_, DI_, DR_);
    gemm3<1><<<dim3(1024, 1), 256, 0, stream>>>(
        dtlH, dtlL, dtwH, dtwL, dt_proj_b, xz, 64, DR_, DR_, 2 * DI_, MROWS);

    // 5) chunked scan; y (gated) written back into xcH/xcL as hi/lo
    scan_passA<<<dim3(DI_ / 256, NC, B_), 256, 0, stream>>>(xz, xcH, xcL, dblP, A_log, hbuf, pbuf, NC);
    scan_combine<<<(B_ * DI_ * 16) / 256, 256, 0, stream>>>(hbuf, pbuf, NC);
    scan_passC<<<dim3(DI_ / 256, NC, B_), 256, 0, stream>>>(xcH, xcL, xz, dblP, A_log, hbuf, Dv, NC);

    // 6) out = y @ out_proj_w^T  (M=8192, N=1024, K=2048); op weights packed into dead xz
    pack_hl<<<(DM_ * DI_ / 4 + 255) / 256, 256, 0, stream>>>(out_proj_w, opH, opL, DM_, DM_, DI_);
    gemm3<0><<<dim3(512, 1), 256, 0, stream>>>(
        (const short*)xcH, (const short*)xcL, opH, opL, nullptr, out, 64, DI_, DI_, DM_, MROWS);
}

// Round 8
// 693.854 us; speedup vs baseline: 6.4918x; 1.0618x over previous
//
#include <hip/hip_runtime.h>
#include <hip/hip_bf16.h>
#include <math.h>

// Problem constants
#define B_   4
#define L_   2048
#define DM_  1024
#define DS_  16
#define DI_  2048          // EXP * DM
#define DR_  64            // (DM+15)//16
#define MROWS (B_ * L_)    // 8192

typedef __attribute__((ext_vector_type(8))) short bf16x8;
typedef __attribute__((ext_vector_type(4))) float f32x4;

__device__ inline float softplusf(float x) {
    return (x > 20.f) ? x : log1pf(expf(x));
}

// ---------------- split fp32 -> bf16 hi/lo (x ~= hi + lo, rel err ~2^-17) ----------------
__device__ inline void splitbf(float x, short& h, short& l) {
    unsigned u = __builtin_bit_cast(unsigned, x);
    unsigned r = (u + 0x7FFFu + ((u >> 16) & 1u)) & 0xFFFF0000u;
    h = (short)(r >> 16);
    float lf = x - __builtin_bit_cast(float, r);
    unsigned u2 = __builtin_bit_cast(unsigned, lf);
    unsigned r2 = u2 + 0x7FFFu + ((u2 >> 16) & 1u);
    l = (short)(r2 >> 16);
}

__device__ inline float bfh2f(unsigned hs) {
    return __builtin_bit_cast(float, hs << 16);
}

// X:[R][Kin] f32 -> H,L:[Ralloc][Kin] bf16, rows >= R zeroed
__global__ __launch_bounds__(256) void pack_hl(
    const float* __restrict__ X, short* __restrict__ H, short* __restrict__ L,
    int R, int Ralloc, int Kin)
{
    int idx = blockIdx.x * 256 + threadIdx.x;       // over Ralloc*Kin/4
    int kq = Kin >> 2;
    if (idx >= Ralloc * kq) return;
    int k4 = (idx % kq) * 4, r = idx / kq;
    short4 hi = make_short4(0,0,0,0), lo = make_short4(0,0,0,0);
    if (r < R) {
        float4 v = *(const float4*)&X[(size_t)r * Kin + k4];
        splitbf(v.x, hi.x, lo.x); splitbf(v.y, hi.y, lo.y);
        splitbf(v.z, hi.z, lo.z); splitbf(v.w, hi.w, lo.w);
    }
    size_t base = (size_t)r * Kin + k4;
    *(short4*)&H[base] = hi;
    *(short4*)&L[base] = lo;
}

__device__ inline void gload_lds16(const void* g, void* s) {
    __builtin_amdgcn_global_load_lds(
        (const __attribute__((address_space(1))) void*)g,
        (__attribute__((address_space(3))) void*)s, 16, 0, 0);
}

// ================= Pipelined MFMA split-bf16 GEMM (in_proj / out_proj) =================
// C[MxN] = A*B^T via HH+HL+LH, BM=256 BN=128 BK=32, 8 waves (2M x 4N), 512 threads.
// Triple-buffered LDS (3 x 48KB), counted vmcnt(6): tile t+2 staged into buf[(t-1)%3]
// (consumed at tile t-1, barrier-separated -> race-free). One s_barrier per K-tile.
// LDS buf layout (shorts): Ah[0,8192) Al[8192,16384) Bh[16384,20480) Bl[20480,24576).
// Linear LDS is bank-conflict-free here: 64B row stride spreads rows across bank halves.
__device__ inline void stage_tile(
    const short* __restrict__ aH, const short* __restrict__ aL,
    const short* __restrict__ bH, const short* __restrict__ bL,
    short* buf, int m0, int n0, int k0, int lda, int tid)
{
    int c0 = tid, c1 = tid + 512;
    int r0 = c0 >> 2, p0 = (c0 & 3) << 3;      // row, element offset (8 elems = 16B)
    int r1 = c1 >> 2, p1 = (c1 & 3) << 3;
    int ub0 = (tid & ~63) * 8;                 // wave-uniform LDS short-offset
    int ub1 = ((tid & ~63) + 512) * 8;
    gload_lds16(&aH[(size_t)(m0 + r0) * lda + k0 + p0], buf + ub0);
    gload_lds16(&aH[(size_t)(m0 + r1) * lda + k0 + p1], buf + ub1);
    gload_lds16(&aL[(size_t)(m0 + r0) * lda + k0 + p0], buf + 8192 + ub0);
    gload_lds16(&aL[(size_t)(m0 + r1) * lda + k0 + p1], buf + 8192 + ub1);
    gload_lds16(&bH[(size_t)(n0 + r0) * lda + k0 + p0], buf + 16384 + ub0);
    gload_lds16(&bL[(size_t)(n0 + r0) * lda + k0 + p0], buf + 20480 + ub0);
}

__global__ __launch_bounds__(512, 2) void gemm_pipe(
    const short* __restrict__ aH, const short* __restrict__ aL,
    const short* __restrict__ bH, const short* __restrict__ bL,
    float* __restrict__ C, int nblocks, int lda, int NT, int ldc)
{
    __shared__ short lds[3 * 24576];
    const int tid = threadIdx.x;
    const int l = tid & 63;
    const int w = tid >> 6;
    const int wr = w >> 2;           // 0..1 (M half: 128 rows)
    const int wn = w & 3;            // 0..3 (N quarter: 32 cols)
    const int lr = l & 15, hk = l >> 4;

    int nwg = gridDim.x;
    int bid = blockIdx.x;
    if ((nwg & 7) == 0) { int cpx = nwg >> 3; bid = (bid & 7) * cpx + (bid >> 3); }
    const int n0 = (bid % nblocks) * 128;    // n-fastest: per-XCD B-panels stay in L2
    const int m0 = (bid / nblocks) * 256;

    f32x4 acc[8][2];
    #pragma unroll
    for (int mi = 0; mi < 8; ++mi)
        #pragma unroll
        for (int ni = 0; ni < 2; ++ni) acc[mi][ni] = (f32x4){0.f, 0.f, 0.f, 0.f};

    // prologue: stage tiles 0,1
    stage_tile(aH, aL, bH, bL, &lds[0],     m0, n0, 0,  lda, tid);
    stage_tile(aH, aL, bH, bL, &lds[24576], m0, n0, 32, lda, tid);
    asm volatile("s_waitcnt vmcnt(6)\ns_barrier" ::: "memory");

    for (int t = 0; t < NT; ++t) {
        short* buf = &lds[(t % 3) * 24576];
        if (t + 2 < NT)
            stage_tile(aH, aL, bH, bL, &lds[((t + 2) % 3) * 24576],
                       m0, n0, (t + 2) * 32, lda, tid);

        bf16x8 Bh[2], Bl[2], Ah[8], Al[8];
        #pragma unroll
        for (int ni = 0; ni < 2; ++ni) {
            int off = 16384 + (wn * 32 + ni * 16 + lr) * 32 + hk * 8;
            Bh[ni] = *(const bf16x8*)&buf[off];
            Bl[ni] = *(const bf16x8*)&buf[off + 4096];
        }
        #pragma unroll
        for (int mi = 0; mi < 8; ++mi) {
            int off = (wr * 128 + mi * 16 + lr) * 32 + hk * 8;
            Ah[mi] = *(const bf16x8*)&buf[off];
            Al[mi] = *(const bf16x8*)&buf[off + 8192];
        }

        __builtin_amdgcn_s_setprio(1);
        #pragma unroll
        for (int mi = 0; mi < 8; ++mi)
            #pragma unroll
            for (int ni = 0; ni < 2; ++ni) {
                acc[mi][ni] = __builtin_amdgcn_mfma_f32_16x16x32_bf16(Ah[mi], Bh[ni], acc[mi][ni], 0, 0, 0);
                acc[mi][ni] = __builtin_amdgcn_mfma_f32_16x16x32_bf16(Ah[mi], Bl[ni], acc[mi][ni], 0, 0, 0);
                acc[mi][ni] = __builtin_amdgcn_mfma_f32_16x16x32_bf16(Al[mi], Bh[ni], acc[mi][ni], 0, 0, 0);
            }
        __builtin_amdgcn_s_setprio(0);

        if (t + 1 < NT) {
            if (t + 2 < NT) asm volatile("s_waitcnt vmcnt(6)\ns_barrier" ::: "memory");
            else            asm volatile("s_waitcnt vmcnt(0)\ns_barrier" ::: "memory");
        }
    }

    #pragma unroll
    for (int mi = 0; mi < 8; ++mi)
        #pragma unroll
        for (int ni = 0; ni < 2; ++ni) {
            int col = n0 + wn * 32 + ni * 16 + lr;
            int rowb = m0 + wr * 128 + mi * 16 + hk * 4;
            #pragma unroll
            for (int j = 0; j < 4; ++j)
                C[(size_t)(rowb + j) * ldc + col] = acc[mi][ni][j];
        }
}

// ================= old fused GEMM (kept for x_proj split-K and dt) =================
template<int EPI>
__global__ __launch_bounds__(256) void gemm3(
    const short* __restrict__ aH, const short* __restrict__ aL,
    const short* __restrict__ bH, const short* __restrict__ bL,
    const float* __restrict__ bias, float* __restrict__ C,
    int mblocks, int lda, int kLen, int ldc, int M)
{
    __shared__ short AsH[128 * 32];
    __shared__ short AsL[128 * 32];
    __shared__ short BsH[128 * 32];
    __shared__ short BsL[128 * 32];

    const int tid = threadIdx.x;
    const int l  = tid & 63;
    const int wr = (tid >> 6) >> 1, wc = (tid >> 6) & 1;
    const int lr = l & 15, lk = l >> 4;

    int nwg = gridDim.x;
    int bid = blockIdx.x;
    if ((nwg & 7) == 0) { int cpx = nwg >> 3; bid = (bid & 7) * cpx + (bid >> 3); }
    const int m0 = (bid % mblocks) * 128;
    const int n0 = (bid / mblocks) * 128;
    const int kOff = blockIdx.y * kLen;

    f32x4 acc[4][4];
    #pragma unroll
    for (int mi = 0; mi < 4; ++mi)
        #pragma unroll
        for (int ni = 0; ni < 4; ++ni) acc[mi][ni] = (f32x4){0.f, 0.f, 0.f, 0.f};

    for (int k0 = 0; k0 < kLen; k0 += 32) {
        int kk = kOff + k0;
        #pragma unroll
        for (int i = 0; i < 2; ++i) {
            int e = i * 256 + tid;
            int row = e >> 2, cc = (e & 3) * 8;
            int sbase = (i * 256 + (tid & ~63)) * 8;
            size_t offA = (size_t)(m0 + row) * lda + kk + cc;
            size_t offB = (size_t)(n0 + row) * lda + kk + cc;
            gload_lds16(&aH[offA], &AsH[sbase]);
            gload_lds16(&aL[offA], &AsL[sbase]);
            gload_lds16(&bH[offB], &BsH[sbase]);
            gload_lds16(&bL[offB], &BsL[sbase]);
        }
        __syncthreads();

        bf16x8 bfh[4], bfl[4];
        #pragma unroll
        for (int ni = 0; ni < 4; ++ni) {
            int boff = (wc * 64 + ni * 16 + lr) * 32 + lk * 8;
            bfh[ni] = *(const bf16x8*)&BsH[boff];
            bfl[ni] = *(const bf16x8*)&BsL[boff];
        }
        #pragma unroll
        for (int mi = 0; mi < 4; ++mi) {
            int aoff = (wr * 64 + mi * 16 + lr) * 32 + lk * 8;
            bf16x8 ah = *(const bf16x8*)&AsH[aoff];
            bf16x8 al = *(const bf16x8*)&AsL[aoff];
            #pragma unroll
            for (int ni = 0; ni < 4; ++ni) {
                acc[mi][ni] = __builtin_amdgcn_mfma_f32_16x16x32_bf16(ah, bfh[ni], acc[mi][ni], 0, 0, 0);
                acc[mi][ni] = __builtin_amdgcn_mfma_f32_16x16x32_bf16(ah, bfl[ni], acc[mi][ni], 0, 0, 0);
                acc[mi][ni] = __builtin_amdgcn_mfma_f32_16x16x32_bf16(al, bfh[ni], acc[mi][ni], 0, 0, 0);
            }
        }
        __syncthreads();
    }

    float* Cp = C;
    if (EPI == 3) Cp = C + (size_t)blockIdx.y * M * ldc;

    #pragma unroll
    for (int mi = 0; mi < 4; ++mi)
        #pragma unroll
        for (int ni = 0; ni < 4; ++ni) {
            int col  = n0 + wc * 64 + ni * 16 + lr;
            int rowb = m0 + wr * 64 + mi * 16 + lk * 4;
            #pragma unroll
            for (int j = 0; j < 4; ++j) {
                float v = acc[mi][ni][j];
                int row = rowb + j;
                if (EPI == 1) v = softplusf(v + bias[col]);
                Cp[(size_t)row * ldc + col] = v;
            }
        }
}

// ---------------- x_proj split-K reduce ----------------
__global__ __launch_bounds__(256) void xproj_reduce(
    const float* __restrict__ part, float* __restrict__ dblP,
    short* __restrict__ dtlH, short* __restrict__ dtlL)
{
    int idx = blockIdx.x * 256 + threadIdx.x;
    if (idx >= MROWS * 128) return;
    int col = idx & 127, row = idx >> 7;
    const size_t S = (size_t)MROWS * 128;
    float s = part[idx] + part[idx + S] + part[idx + 2 * S] + part[idx + 3 * S];
    if (col < 96) dblP[(size_t)row * 96 + col] = s;
    if (col < 64) {
        short h, lo; splitbf(s, h, lo);
        dtlH[(size_t)row * 64 + col] = h;
        dtlL[(size_t)row * 64 + col] = lo;
    }
}

// ---------------- Depthwise causal conv (DC=4) + SiLU, output split hi/lo ----------------
__global__ __launch_bounds__(256) void conv_silu_split(
    const float* __restrict__ xz, const float* __restrict__ cw,
    const float* __restrict__ cb, ushort* __restrict__ xcH, ushort* __restrict__ xcL)
{
    int t = blockIdx.x * 256 + threadIdx.x;
    if (t >= B_ * L_ * DI_ / 4) return;
    int d4 = (t & (DI_ / 4 - 1)) * 4;
    int ll = (t >> 9) & (L_ - 1);
    int b  = t >> 20;

    float4 w0 = *(const float4*)&cw[(d4 + 0) * 4];
    float4 w1 = *(const float4*)&cw[(d4 + 1) * 4];
    float4 w2 = *(const float4*)&cw[(d4 + 2) * 4];
    float4 w3 = *(const float4*)&cw[(d4 + 3) * 4];
    float4 bb = *(const float4*)&cb[d4];
    float a0 = bb.x, a1 = bb.y, a2 = bb.z, a3 = bb.w;

    size_t rb = (size_t)(b * L_) * 4096 + d4;
    if (ll >= 3) { float4 x = *(const float4*)&xz[rb + (size_t)(ll - 3) * 4096];
                   a0 += x.x * w0.x; a1 += x.y * w1.x; a2 += x.z * w2.x; a3 += x.w * w3.x; }
    if (ll >= 2) { float4 x = *(const float4*)&xz[rb + (size_t)(ll - 2) * 4096];
                   a0 += x.x * w0.y; a1 += x.y * w1.y; a2 += x.z * w2.y; a3 += x.w * w3.y; }
    if (ll >= 1) { float4 x = *(const float4*)&xz[rb + (size_t)(ll - 1) * 4096];
                   a0 += x.x * w0.z; a1 += x.y * w1.z; a2 += x.z * w2.z; a3 += x.w * w3.z; }
    {            float4 x = *(const float4*)&xz[rb + (size_t)ll * 4096];
                   a0 += x.x * w0.w; a1 += x.y * w1.w; a2 += x.z * w2.w; a3 += x.w * w3.w; }

    a0 *= 1.f / (1.f + __expf(-a0));
    a1 *= 1.f / (1.f + __expf(-a1));
    a2 *= 1.f / (1.f + __expf(-a2));
    a3 *= 1.f / (1.f + __expf(-a3));

    short4 hi, lo;
    splitbf(a0, hi.x, lo.x); splitbf(a1, hi.y, lo.y);
    splitbf(a2, hi.z, lo.z); splitbf(a3, hi.w, lo.w);
    size_t oidx = (size_t)(b * L_ + ll) * DI_ + d4;
    *(short4*)&xcH[oidx] = hi;
    *(short4*)&xcL[oidx] = lo;
}

// ---------------- Chunked selective scan ----------------
__global__ __launch_bounds__(256) void scan_passA(
    const float* __restrict__ xz, const ushort* __restrict__ xcH, const ushort* __restrict__ xcL,
    const float* __restrict__ dbl, const float* __restrict__ A_log,
    float* __restrict__ hbuf, float* __restrict__ pbuf, int NC)
{
    __shared__ float sB[128][16];
    const int CL = L_ / NC;
    const int d = blockIdx.x * 256 + threadIdx.x;
    const int c = blockIdx.y, b = blockIdx.z;
    const int row0 = b * L_ + c * CL;

    for (int e = threadIdx.x; e < CL * 16; e += 256) {
        int tt = e >> 4, n = e & 15;
        sB[tt][n] = dbl[(size_t)(row0 + tt) * 96 + 64 + n];
    }
    __syncthreads();

    float A[16], h[16];
    #pragma unroll
    for (int i = 0; i < 16; ++i) { A[i] = -__expf(A_log[d * 16 + i]); h[i] = 0.f; }
    float sumdt = 0.f;

    for (int tt = 0; tt < CL; ++tt) {
        size_t base = (size_t)(row0 + tt);
        float dtv = xz[base * 4096 + d];
        float xv  = bfh2f(xcH[base * 2048 + d]) + bfh2f(xcL[base * 2048 + d]);
        float dtx = dtv * xv;
        sumdt += dtv;
        #pragma unroll
        for (int i = 0; i < 16; ++i) {
            float dA = __expf(dtv * A[i]);
            h[i] = h[i] * dA + dtx * sB[tt][i];
        }
    }

    size_t sidx = (((size_t)b * NC + c) * DI_ + d) * 16;
    #pragma unroll
    for (int i = 0; i < 16; i += 4) {
        *(float4*)&hbuf[sidx + i] = make_float4(h[i], h[i+1], h[i+2], h[i+3]);
        *(float4*)&pbuf[sidx + i] = make_float4(__expf(A[i]   * sumdt), __expf(A[i+1] * sumdt),
                                                __expf(A[i+2] * sumdt), __expf(A[i+3] * sumdt));
    }
}

__global__ __launch_bounds__(256) void scan_combine(
    float* __restrict__ hbuf, const float* __restrict__ pbuf, int NC)
{
    int g = blockIdx.x * 256 + threadIdx.x;
    int n = g & 15;
    int d = (g >> 4) & (DI_ - 1);
    int b = g >> 15;
    float hin = 0.f;
    for (int c = 0; c < NC; ++c) {
        size_t idx = (((size_t)b * NC + c) * DI_ + d) * 16 + n;
        float ho = hbuf[idx], p = pbuf[idx];
        hbuf[idx] = hin;
        hin = ho + p * hin;
    }
}

__global__ __launch_bounds__(256) void scan_passC(
    ushort* __restrict__ xcH, ushort* __restrict__ xcL, const float* __restrict__ xz,
    const float* __restrict__ dbl, const float* __restrict__ A_log,
    const float* __restrict__ hbuf, const float* __restrict__ Dp, int NC)
{
    __shared__ float sBC[128][32];
    const int CL = L_ / NC;
    const int d = blockIdx.x * 256 + threadIdx.x;
    const int c = blockIdx.y, b = blockIdx.z;
    const int row0 = b * L_ + c * CL;

    for (int e = threadIdx.x; e < CL * 32; e += 256) {
        int tt = e >> 5, k = e & 31;
        sBC[tt][k] = dbl[(size_t)(row0 + tt) * 96 + 64 + k];
    }
    __syncthreads();

    float A[16], h[16];
    size_t sidx = (((size_t)b * NC + c) * DI_ + d) * 16;
    #pragma unroll
    for (int i = 0; i < 16; i += 4) {
        float4 v = *(const float4*)&hbuf[sidx + i];
        h[i] = v.x; h[i+1] = v.y; h[i+2] = v.z; h[i+3] = v.w;
    }
    #pragma unroll
    for (int i = 0; i < 16; ++i) A[i] = -__expf(A_log[d * 16 + i]);
    const float Dd = Dp[d];

    for (int tt = 0; tt < CL; ++tt) {
        size_t base = (size_t)(row0 + tt);
        float dtv = xz[base * 4096 + d];
        float xv  = bfh2f(xcH[base * 2048 + d]) + bfh2f(xcL[base * 2048 + d]);
        float zv  = xz[base * 4096 + 2048 + d];
        float dtx = dtv * xv;
        float y = 0.f;
        #pragma unroll
        for (int i = 0; i < 16; ++i) {
            float dA = __expf(dtv * A[i]);
            h[i] = h[i] * dA + dtx * sBC[tt][i];
            y = fmaf(h[i], sBC[tt][16 + i], y);
        }
        float yt = y + xv * Dd;
        float sig = 1.f / (1.f + __expf(-zv));
        float ov = yt * (zv * sig);
        short hh, lo; splitbf(ov, hh, lo);
        xcH[base * 2048 + d] = (ushort)hh;
        xcL[base * 2048 + d] = (ushort)lo;
    }
}

// ---------------- Launch ----------------
extern "C" void kernel_launch(void* const* d_in, const int* in_sizes, int n_in,
                              void* d_out, int out_size, void* d_ws, size_t ws_size,
                              hipStream_t stream)
{
    const float* u         = (const float*)d_in[0];
    const float* in_proj_w = (const float*)d_in[1];
    const float* conv_w    = (const float*)d_in[2];
    const float* conv_b    = (const float*)d_in[3];
    const float* x_proj_w  = (const float*)d_in[4];
    const float* dt_proj_w = (const float*)d_in[5];
    const float* dt_proj_b = (const float*)d_in[6];
    const float* A_log     = (const float*)d_in[7];
    const float* Dv        = (const float*)d_in[8];
    const float* out_proj_w= (const float*)d_in[9];
    float* out = (float*)d_out;

    const size_t MB = 1024ull * 1024ull;
    char* ws = (char*)d_ws;
    // ws (195 MiB, proven): xz f32 @0 (128M) | xcH bf16 @128M (32M) | xcL @160M (32M) | dblP @192M (3M)
    float*  xz   = (float*)(ws);
    ushort* xcH  = (ushort*)(ws + 128 * MB);
    ushort* xcL  = (ushort*)(ws + 160 * MB);
    float*  dblP = (float*)(ws + 192 * MB);
    short*  uH   = (short*)(ws + 128 * MB);           // 16 MiB (dead after in_proj)
    short*  uL   = (short*)(ws + 144 * MB);           // 16 MiB
    short*  wiH  = (short*)(ws + 160 * MB);           //  8 MiB
    short*  wiL  = (short*)(ws + 168 * MB);           //  8 MiB
    short*  opH  = (short*)(ws);                      //  4 MiB (xz dead post-scan)
    short*  opL  = (short*)(ws + 4 * MB);             //  4 MiB

    // d_out (32 MiB) scratch until final GEMM overwrites it all
    char* doc = (char*)d_out;
    float* xpart = (float*)(doc);                     // 16M (x_proj partials)
    float* hbuf = (float*)(doc);                      // 8M  (after reduce)
    float* pbuf = (float*)(doc + 8 * MB);             // 8M
    short* xpH  = (short*)(doc + 16 * MB);
    short* xpL  = (short*)(doc + 16 * MB + 512 * 1024);
    short* dtwH = (short*)(doc + 17 * MB);
    short* dtwL = (short*)(doc + 17 * MB + 256 * 1024);
    short* dtlH = (short*)(doc + 18 * MB);
    short* dtlL = (short*)(doc + 19 * MB);
    const int NC = 16;

    // 1) pack u + in_proj_w; xz = u @ in_proj_w^T  (M=8192, N=4096, K=1024) -- pipelined
    pack_hl<<<(MROWS * DM_ / 4 + 255) / 256, 256, 0, stream>>>(u, uH, uL, MROWS, MROWS, DM_);
    pack_hl<<<(4096 * DM_ / 4 + 255) / 256, 256, 0, stream>>>(in_proj_w, wiH, wiL, 4096, 4096, DM_);
    gemm_pipe<<<dim3(32 * 32), 512, 0, stream>>>(
        uH, uL, wiH, wiL, xz, /*nblocks=*/32, /*lda=*/DM_, /*NT=*/DM_ / 32, /*ldc=*/2 * DI_);

    // 2) conv + silu -> xcH/xcL (split)
    conv_silu_split<<<(B_ * L_ * DI_ / 4 + 255) / 256, 256, 0, stream>>>(
        xz, conv_w, conv_b, xcH, xcL);

    // 3) x_proj: split-K=4 partials -> reduce (writes dblP + dt-input split)
    pack_hl<<<(128 * DI_ / 4 + 255) / 256, 256, 0, stream>>>(x_proj_w, xpH, xpL, 96, 128, DI_);
    gemm3<3><<<dim3(64, 4), 256, 0, stream>>>(
        (const short*)xcH, (const short*)xcL, xpH, xpL, nullptr, xpart, 64, DI_, DI_ / 4, 128, MROWS);
    xproj_reduce<<<(MROWS * 128) / 256, 256, 0, stream>>>(xpart, dblP, dtlH, dtlL);

    // 4) dt = softplus(dtl @ dt_proj_w^T + b) -> x-half of xz (ldc=4096)
    pack_hl<<<(DI_ * DR_ / 4 + 255) / 256, 256, 0, stream>>>(dt_proj_w, dtwH, dtwL, DI_, DI_, DR_);
    gemm3<1><<<dim3(1024, 1), 256, 0, stream>>>(
        dtlH, dtlL, dtwH, dtwL, dt_proj_b, xz, 64, DR_, DR_, 2 * DI_, MROWS);

    // 5) chunked scan; y (gated) written back into xcH/xcL as hi/lo
    scan_passA<<<dim3(DI_ / 256, NC, B_), 256, 0, stream>>>(xz, xcH, xcL, dblP, A_log, hbuf, pbuf, NC);
    scan_combine<<<(B_ * DI_ * 16) / 256, 256, 0, stream>>>(hbuf, pbuf, NC);
    scan_passC<<<dim3(DI_ / 256, NC, B_), 256, 0, stream>>>(xcH, xcL, xz, dblP, A_log, hbuf, Dv, NC);

    // 6) out = y @ out_proj_w^T  (M=8192, N=1024, K=2048) -- pipelined
    pack_hl<<<(DM_ * DI_ / 4 + 255) / 256, 256, 0, stream>>>(out_proj_w, opH, opL, DM_, DM_, DI_);
    gemm_pipe<<<dim3(32 * 8), 512, 0, stream>>>(
        (const short*)xcH, (const short*)xcL, opH, opL, out, /*nblocks=*/8, /*lda=*/DI_, /*NT=*/DI_ / 32, /*ldc=*/DM_);
}

// Round 9
// 662.916 us; speedup vs baseline: 6.7948x; 1.0467x over previous
//
#include <hip/hip_runtime.h>
#include <hip/hip_bf16.h>
#include <math.h>

// Problem constants
#define B_   4
#define L_   2048
#define DM_  1024
#define DS_  16
#define DI_  2048          // EXP * DM
#define DR_  64            // (DM+15)//16
#define MROWS (B_ * L_)    // 8192

typedef __attribute__((ext_vector_type(8))) short bf16x8;
typedef __attribute__((ext_vector_type(4))) float f32x4;

__device__ inline float softplusf(float x) {
    return (x > 20.f) ? x : log1pf(expf(x));
}

// ---------------- split fp32 -> bf16 hi/lo (x ~= hi + lo, rel err ~2^-17) ----------------
__device__ inline void splitbf(float x, short& h, short& l) {
    unsigned u = __builtin_bit_cast(unsigned, x);
    unsigned r = (u + 0x7FFFu + ((u >> 16) & 1u)) & 0xFFFF0000u;
    h = (short)(r >> 16);
    float lf = x - __builtin_bit_cast(float, r);
    unsigned u2 = __builtin_bit_cast(unsigned, lf);
    unsigned r2 = u2 + 0x7FFFu + ((u2 >> 16) & 1u);
    l = (short)(r2 >> 16);
}

__device__ inline float bfh2f(unsigned hs) {
    return __builtin_bit_cast(float, hs << 16);
}

// X:[R][Kin] f32 -> H,L:[Ralloc][Kin] bf16, rows >= R zeroed
__global__ __launch_bounds__(256) void pack_hl(
    const float* __restrict__ X, short* __restrict__ H, short* __restrict__ L,
    int R, int Ralloc, int Kin)
{
    int idx = blockIdx.x * 256 + threadIdx.x;       // over Ralloc*Kin/4
    int kq = Kin >> 2;
    if (idx >= Ralloc * kq) return;
    int k4 = (idx % kq) * 4, r = idx / kq;
    short4 hi = make_short4(0,0,0,0), lo = make_short4(0,0,0,0);
    if (r < R) {
        float4 v = *(const float4*)&X[(size_t)r * Kin + k4];
        splitbf(v.x, hi.x, lo.x); splitbf(v.y, hi.y, lo.y);
        splitbf(v.z, hi.z, lo.z); splitbf(v.w, hi.w, lo.w);
    }
    size_t base = (size_t)r * Kin + k4;
    *(short4*)&H[base] = hi;
    *(short4*)&L[base] = lo;
}

__device__ inline void gload_lds16(const void* g, void* s) {
    __builtin_amdgcn_global_load_lds(
        (const __attribute__((address_space(1))) void*)g,
        (__attribute__((address_space(3))) void*)s, 16, 0, 0);
}

// ================= Pipelined MFMA split-bf16 GEMM (in_proj / out_proj) =================
// C[MxN] = A*B^T via HH+HL+LH, BM=256 BN=128 BK=32, 8 waves as 4M x 2N (wave tile 64x64,
// 4x4 frags -> 16 ds_read_b128 per 48 MFMA: best LDS-reuse ratio). 512 threads.
// Triple-buffered LDS (3 x 48KB), counted vmcnt(6): tile t+2 staged into buf[(t-1)%3]
// (its last reader finished before tile t began -> race-free). One s_barrier per K-tile.
// LDS buf layout (shorts): Ah[0,8192) Al[8192,16384) Bh[16384,20480) Bl[20480,24576).
__device__ inline void stage_tile(
    const short* __restrict__ aH, const short* __restrict__ aL,
    const short* __restrict__ bH, const short* __restrict__ bL,
    short* buf, int m0, int n0, int k0, int lda, int tid)
{
    int c0 = tid, c1 = tid + 512;
    int r0 = c0 >> 2, p0 = (c0 & 3) << 3;      // row, element offset (8 elems = 16B)
    int r1 = c1 >> 2, p1 = (c1 & 3) << 3;
    int ub0 = (tid & ~63) * 8;                 // wave-uniform LDS short-offset
    int ub1 = ((tid & ~63) + 512) * 8;
    gload_lds16(&aH[(size_t)(m0 + r0) * lda + k0 + p0], buf + ub0);
    gload_lds16(&aH[(size_t)(m0 + r1) * lda + k0 + p1], buf + ub1);
    gload_lds16(&aL[(size_t)(m0 + r0) * lda + k0 + p0], buf + 8192 + ub0);
    gload_lds16(&aL[(size_t)(m0 + r1) * lda + k0 + p1], buf + 8192 + ub1);
    gload_lds16(&bH[(size_t)(n0 + r0) * lda + k0 + p0], buf + 16384 + ub0);
    gload_lds16(&bL[(size_t)(n0 + r0) * lda + k0 + p0], buf + 20480 + ub0);
}

__global__ __launch_bounds__(512, 2) void gemm_pipe(
    const short* __restrict__ aH, const short* __restrict__ aL,
    const short* __restrict__ bH, const short* __restrict__ bL,
    float* __restrict__ C, int nblocks, int lda, int NT, int ldc)
{
    __shared__ short lds[3 * 24576];
    const int tid = threadIdx.x;
    const int l = tid & 63;
    const int w = tid >> 6;
    const int wm = w & 3;            // 0..3 (M quarter: 64 rows)
    const int wn = w >> 2;           // 0..1 (N half: 64 cols)
    const int lr = l & 15, hk = l >> 4;

    int nwg = gridDim.x;
    int bid = blockIdx.x;
    if ((nwg & 7) == 0) { int cpx = nwg >> 3; bid = (bid & 7) * cpx + (bid >> 3); }
    const int n0 = (bid % nblocks) * 128;
    const int m0 = (bid / nblocks) * 256;

    f32x4 acc[4][4];
    #pragma unroll
    for (int mi = 0; mi < 4; ++mi)
        #pragma unroll
        for (int ni = 0; ni < 4; ++ni) acc[mi][ni] = (f32x4){0.f, 0.f, 0.f, 0.f};

    // prologue: stage tiles 0,1
    stage_tile(aH, aL, bH, bL, &lds[0],     m0, n0, 0,  lda, tid);
    stage_tile(aH, aL, bH, bL, &lds[24576], m0, n0, 32, lda, tid);
    asm volatile("s_waitcnt vmcnt(6)\ns_barrier" ::: "memory");

    for (int t = 0; t < NT; ++t) {
        short* buf = &lds[(t % 3) * 24576];
        if (t + 2 < NT)
            stage_tile(aH, aL, bH, bL, &lds[((t + 2) % 3) * 24576],
                       m0, n0, (t + 2) * 32, lda, tid);

        bf16x8 Ah[4], Al[4], Bh[4], Bl[4];
        #pragma unroll
        for (int ni = 0; ni < 4; ++ni) {
            int off = 16384 + (wn * 64 + ni * 16 + lr) * 32 + hk * 8;
            Bh[ni] = *(const bf16x8*)&buf[off];
            Bl[ni] = *(const bf16x8*)&buf[off + 4096];
        }
        #pragma unroll
        for (int mi = 0; mi < 4; ++mi) {
            int off = (wm * 64 + mi * 16 + lr) * 32 + hk * 8;
            Ah[mi] = *(const bf16x8*)&buf[off];
            Al[mi] = *(const bf16x8*)&buf[off + 8192];
        }

        __builtin_amdgcn_s_setprio(1);
        #pragma unroll
        for (int mi = 0; mi < 4; ++mi)
            #pragma unroll
            for (int ni = 0; ni < 4; ++ni) {
                acc[mi][ni] = __builtin_amdgcn_mfma_f32_16x16x32_bf16(Ah[mi], Bh[ni], acc[mi][ni], 0, 0, 0);
                acc[mi][ni] = __builtin_amdgcn_mfma_f32_16x16x32_bf16(Ah[mi], Bl[ni], acc[mi][ni], 0, 0, 0);
                acc[mi][ni] = __builtin_amdgcn_mfma_f32_16x16x32_bf16(Al[mi], Bh[ni], acc[mi][ni], 0, 0, 0);
            }
        __builtin_amdgcn_s_setprio(0);

        if (t + 1 < NT) {
            if (t + 2 < NT) asm volatile("s_waitcnt vmcnt(6)\ns_barrier" ::: "memory");
            else            asm volatile("s_waitcnt vmcnt(0)\ns_barrier" ::: "memory");
        }
    }

    #pragma unroll
    for (int mi = 0; mi < 4; ++mi)
        #pragma unroll
        for (int ni = 0; ni < 4; ++ni) {
            int col = n0 + wn * 64 + ni * 16 + lr;
            int rowb = m0 + wm * 64 + mi * 16 + hk * 4;
            #pragma unroll
            for (int j = 0; j < 4; ++j)
                C[(size_t)(rowb + j) * ldc + col] = acc[mi][ni][j];
        }
}

// ================= old fused GEMM (kept for x_proj split-K and dt) =================
template<int EPI>
__global__ __launch_bounds__(256) void gemm3(
    const short* __restrict__ aH, const short* __restrict__ aL,
    const short* __restrict__ bH, const short* __restrict__ bL,
    const float* __restrict__ bias, float* __restrict__ C,
    int mblocks, int lda, int kLen, int ldc, int M)
{
    __shared__ short AsH[128 * 32];
    __shared__ short AsL[128 * 32];
    __shared__ short BsH[128 * 32];
    __shared__ short BsL[128 * 32];

    const int tid = threadIdx.x;
    const int l  = tid & 63;
    const int wr = (tid >> 6) >> 1, wc = (tid >> 6) & 1;
    const int lr = l & 15, lk = l >> 4;

    int nwg = gridDim.x;
    int bid = blockIdx.x;
    if ((nwg & 7) == 0) { int cpx = nwg >> 3; bid = (bid & 7) * cpx + (bid >> 3); }
    const int m0 = (bid % mblocks) * 128;
    const int n0 = (bid / mblocks) * 128;
    const int kOff = blockIdx.y * kLen;

    f32x4 acc[4][4];
    #pragma unroll
    for (int mi = 0; mi < 4; ++mi)
        #pragma unroll
        for (int ni = 0; ni < 4; ++ni) acc[mi][ni] = (f32x4){0.f, 0.f, 0.f, 0.f};

    for (int k0 = 0; k0 < kLen; k0 += 32) {
        int kk = kOff + k0;
        #pragma unroll
        for (int i = 0; i < 2; ++i) {
            int e = i * 256 + tid;
            int row = e >> 2, cc = (e & 3) * 8;
            int sbase = (i * 256 + (tid & ~63)) * 8;
            size_t offA = (size_t)(m0 + row) * lda + kk + cc;
            size_t offB = (size_t)(n0 + row) * lda + kk + cc;
            gload_lds16(&aH[offA], &AsH[sbase]);
            gload_lds16(&aL[offA], &AsL[sbase]);
            gload_lds16(&bH[offB], &BsH[sbase]);
            gload_lds16(&bL[offB], &BsL[sbase]);
        }
        __syncthreads();

        bf16x8 bfh[4], bfl[4];
        #pragma unroll
        for (int ni = 0; ni < 4; ++ni) {
            int boff = (wc * 64 + ni * 16 + lr) * 32 + lk * 8;
            bfh[ni] = *(const bf16x8*)&BsH[boff];
            bfl[ni] = *(const bf16x8*)&BsL[boff];
        }
        #pragma unroll
        for (int mi = 0; mi < 4; ++mi) {
            int aoff = (wr * 64 + mi * 16 + lr) * 32 + lk * 8;
            bf16x8 ah = *(const bf16x8*)&AsH[aoff];
            bf16x8 al = *(const bf16x8*)&AsL[aoff];
            #pragma unroll
            for (int ni = 0; ni < 4; ++ni) {
                acc[mi][ni] = __builtin_amdgcn_mfma_f32_16x16x32_bf16(ah, bfh[ni], acc[mi][ni], 0, 0, 0);
                acc[mi][ni] = __builtin_amdgcn_mfma_f32_16x16x32_bf16(ah, bfl[ni], acc[mi][ni], 0, 0, 0);
                acc[mi][ni] = __builtin_amdgcn_mfma_f32_16x16x32_bf16(al, bfh[ni], acc[mi][ni], 0, 0, 0);
            }
        }
        __syncthreads();
    }

    float* Cp = C;
    if (EPI == 3) Cp = C + (size_t)blockIdx.y * M * ldc;

    #pragma unroll
    for (int mi = 0; mi < 4; ++mi)
        #pragma unroll
        for (int ni = 0; ni < 4; ++ni) {
            int col  = n0 + wc * 64 + ni * 16 + lr;
            int rowb = m0 + wr * 64 + mi * 16 + lk * 4;
            #pragma unroll
            for (int j = 0; j < 4; ++j) {
                float v = acc[mi][ni][j];
                int row = rowb + j;
                if (EPI == 1) v = softplusf(v + bias[col]);
                Cp[(size_t)row * ldc + col] = v;
            }
        }
}

// ---------------- x_proj split-K reduce ----------------
__global__ __launch_bounds__(256) void xproj_reduce(
    const float* __restrict__ part, float* __restrict__ dblP,
    short* __restrict__ dtlH, short* __restrict__ dtlL)
{
    int idx = blockIdx.x * 256 + threadIdx.x;
    if (idx >= MROWS * 128) return;
    int col = idx & 127, row = idx >> 7;
    const size_t S = (size_t)MROWS * 128;
    float s = part[idx] + part[idx + S] + part[idx + 2 * S] + part[idx + 3 * S];
    if (col < 96) dblP[(size_t)row * 96 + col] = s;
    if (col < 64) {
        short h, lo; splitbf(s, h, lo);
        dtlH[(size_t)row * 64 + col] = h;
        dtlL[(size_t)row * 64 + col] = lo;
    }
}

// ---------------- Depthwise causal conv (DC=4) + SiLU, output split hi/lo ----------------
__global__ __launch_bounds__(256) void conv_silu_split(
    const float* __restrict__ xz, const float* __restrict__ cw,
    const float* __restrict__ cb, ushort* __restrict__ xcH, ushort* __restrict__ xcL)
{
    int t = blockIdx.x * 256 + threadIdx.x;
    if (t >= B_ * L_ * DI_ / 4) return;
    int d4 = (t & (DI_ / 4 - 1)) * 4;
    int ll = (t >> 9) & (L_ - 1);
    int b  = t >> 20;

    float4 w0 = *(const float4*)&cw[(d4 + 0) * 4];
    float4 w1 = *(const float4*)&cw[(d4 + 1) * 4];
    float4 w2 = *(const float4*)&cw[(d4 + 2) * 4];
    float4 w3 = *(const float4*)&cw[(d4 + 3) * 4];
    float4 bb = *(const float4*)&cb[d4];
    float a0 = bb.x, a1 = bb.y, a2 = bb.z, a3 = bb.w;

    size_t rb = (size_t)(b * L_) * 4096 + d4;
    if (ll >= 3) { float4 x = *(const float4*)&xz[rb + (size_t)(ll - 3) * 4096];
                   a0 += x.x * w0.x; a1 += x.y * w1.x; a2 += x.z * w2.x; a3 += x.w * w3.x; }
    if (ll >= 2) { float4 x = *(const float4*)&xz[rb + (size_t)(ll - 2) * 4096];
                   a0 += x.x * w0.y; a1 += x.y * w1.y; a2 += x.z * w2.y; a3 += x.w * w3.y; }
    if (ll >= 1) { float4 x = *(const float4*)&xz[rb + (size_t)(ll - 1) * 4096];
                   a0 += x.x * w0.z; a1 += x.y * w1.z; a2 += x.z * w2.z; a3 += x.w * w3.z; }
    {            float4 x = *(const float4*)&xz[rb + (size_t)ll * 4096];
                   a0 += x.x * w0.w; a1 += x.y * w1.w; a2 += x.z * w2.w; a3 += x.w * w3.w; }

    a0 *= 1.f / (1.f + __expf(-a0));
    a1 *= 1.f / (1.f + __expf(-a1));
    a2 *= 1.f / (1.f + __expf(-a2));
    a3 *= 1.f / (1.f + __expf(-a3));

    short4 hi, lo;
    splitbf(a0, hi.x, lo.x); splitbf(a1, hi.y, lo.y);
    splitbf(a2, hi.z, lo.z); splitbf(a3, hi.w, lo.w);
    size_t oidx = (size_t)(b * L_ + ll) * DI_ + d4;
    *(short4*)&xcH[oidx] = hi;
    *(short4*)&xcL[oidx] = lo;
}

// ---------------- Chunked selective scan ----------------
__global__ __launch_bounds__(256) void scan_passA(
    const float* __restrict__ xz, const ushort* __restrict__ xcH, const ushort* __restrict__ xcL,
    const float* __restrict__ dbl, const float* __restrict__ A_log,
    float* __restrict__ hbuf, float* __restrict__ pbuf, int NC)
{
    __shared__ float sB[128][16];
    const int CL = L_ / NC;
    const int d = blockIdx.x * 256 + threadIdx.x;
    const int c = blockIdx.y, b = blockIdx.z;
    const int row0 = b * L_ + c * CL;

    for (int e = threadIdx.x; e < CL * 16; e += 256) {
        int tt = e >> 4, n = e & 15;
        sB[tt][n] = dbl[(size_t)(row0 + tt) * 96 + 64 + n];
    }
    __syncthreads();

    float A[16], h[16];
    #pragma unroll
    for (int i = 0; i < 16; ++i) { A[i] = -__expf(A_log[d * 16 + i]); h[i] = 0.f; }
    float sumdt = 0.f;

    for (int tt = 0; tt < CL; ++tt) {
        size_t base = (size_t)(row0 + tt);
        float dtv = xz[base * 4096 + d];
        float xv  = bfh2f(xcH[base * 2048 + d]) + bfh2f(xcL[base * 2048 + d]);
        float dtx = dtv * xv;
        sumdt += dtv;
        #pragma unroll
        for (int i = 0; i < 16; ++i) {
            float dA = __expf(dtv * A[i]);
            h[i] = h[i] * dA + dtx * sB[tt][i];
        }
    }

    size_t sidx = (((size_t)b * NC + c) * DI_ + d) * 16;
    #pragma unroll
    for (int i = 0; i < 16; i += 4) {
        *(float4*)&hbuf[sidx + i] = make_float4(h[i], h[i+1], h[i+2], h[i+3]);
        *(float4*)&pbuf[sidx + i] = make_float4(__expf(A[i]   * sumdt), __expf(A[i+1] * sumdt),
                                                __expf(A[i+2] * sumdt), __expf(A[i+3] * sumdt));
    }
}

__global__ __launch_bounds__(256) void scan_combine(
    float* __restrict__ hbuf, const float* __restrict__ pbuf, int NC)
{
    int g = blockIdx.x * 256 + threadIdx.x;
    int n = g & 15;
    int d = (g >> 4) & (DI_ - 1);
    int b = g >> 15;
    float hin = 0.f;
    for (int c = 0; c < NC; ++c) {
        size_t idx = (((size_t)b * NC + c) * DI_ + d) * 16 + n;
        float ho = hbuf[idx], p = pbuf[idx];
        hbuf[idx] = hin;
        hin = ho + p * hin;
    }
}

__global__ __launch_bounds__(256) void scan_passC(
    ushort* __restrict__ xcH, ushort* __restrict__ xcL, const float* __restrict__ xz,
    const float* __restrict__ dbl, const float* __restrict__ A_log,
    const float* __restrict__ hbuf, const float* __restrict__ Dp, int NC)
{
    __shared__ float sBC[128][32];
    const int CL = L_ / NC;
    const int d = blockIdx.x * 256 + threadIdx.x;
    const int c = blockIdx.y, b = blockIdx.z;
    const int row0 = b * L_ + c * CL;

    for (int e = threadIdx.x; e < CL * 32; e += 256) {
        int tt = e >> 5, k = e & 31;
        sBC[tt][k] = dbl[(size_t)(row0 + tt) * 96 + 64 + k];
    }
    __syncthreads();

    float A[16], h[16];
    size_t sidx = (((size_t)b * NC + c) * DI_ + d) * 16;
    #pragma unroll
    for (int i = 0; i < 16; i += 4) {
        float4 v = *(const float4*)&hbuf[sidx + i];
        h[i] = v.x; h[i+1] = v.y; h[i+2] = v.z; h[i+3] = v.w;
    }
    #pragma unroll
    for (int i = 0; i < 16; ++i) A[i] = -__expf(A_log[d * 16 + i]);
    const float Dd = Dp[d];

    for (int tt = 0; tt < CL; ++tt) {
        size_t base = (size_t)(row0 + tt);
        float dtv = xz[base * 4096 + d];
        float xv  = bfh2f(xcH[base * 2048 + d]) + bfh2f(xcL[base * 2048 + d]);
        float zv  = xz[base * 4096 + 2048 + d];
        float dtx = dtv * xv;
        float y = 0.f;
        #pragma unroll
        for (int i = 0; i < 16; ++i) {
            float dA = __expf(dtv * A[i]);
            h[i] = h[i] * dA + dtx * sBC[tt][i];
            y = fmaf(h[i], sBC[tt][16 + i], y);
        }
        float yt = y + xv * Dd;
        float sig = 1.f / (1.f + __expf(-zv));
        float ov = yt * (zv * sig);
        short hh, lo; splitbf(ov, hh, lo);
        xcH[base * 2048 + d] = (ushort)hh;
        xcL[base * 2048 + d] = (ushort)lo;
    }
}

// ---------------- Launch ----------------
extern "C" void kernel_launch(void* const* d_in, const int* in_sizes, int n_in,
                              void* d_out, int out_size, void* d_ws, size_t ws_size,
                              hipStream_t stream)
{
    const float* u         = (const float*)d_in[0];
    const float* in_proj_w = (const float*)d_in[1];
    const float* conv_w    = (const float*)d_in[2];
    const float* conv_b    = (const float*)d_in[3];
    const float* x_proj_w  = (const float*)d_in[4];
    const float* dt_proj_w = (const float*)d_in[5];
    const float* dt_proj_b = (const float*)d_in[6];
    const float* A_log     = (const float*)d_in[7];
    const float* Dv        = (const float*)d_in[8];
    const float* out_proj_w= (const float*)d_in[9];
    float* out = (float*)d_out;

    const size_t MB = 1024ull * 1024ull;
    char* ws = (char*)d_ws;
    // ws (195 MiB fixed): xz f32 @0 (128M) | xcH bf16 @128M (32M) | xcL @160M (32M) | dblP @192M (3M)
    float*  xz   = (float*)(ws);
    ushort* xcH  = (ushort*)(ws + 128 * MB);
    ushort* xcL  = (ushort*)(ws + 160 * MB);
    float*  dblP = (float*)(ws + 192 * MB);
    short*  uH   = (short*)(ws + 128 * MB);           // 16 MiB (dead after in_proj)
    short*  uL   = (short*)(ws + 144 * MB);           // 16 MiB
    short*  wiH  = (short*)(ws + 160 * MB);           //  8 MiB
    short*  wiL  = (short*)(ws + 168 * MB);           //  8 MiB
    short*  opH  = (short*)(ws);                      //  4 MiB (xz dead post-scan)
    short*  opL  = (short*)(ws + 4 * MB);             //  4 MiB
    size_t off_tail = 195 * MB;

    // d_out (32 MiB) scratch until final GEMM overwrites it all
    char* doc = (char*)d_out;
    float* xpart = (float*)(doc);                     // 16M (x_proj partials)
    short* xpH  = (short*)(doc + 16 * MB);
    short* xpL  = (short*)(doc + 16 * MB + 512 * 1024);
    short* dtwH = (short*)(doc + 17 * MB);
    short* dtwL = (short*)(doc + 17 * MB + 256 * 1024);
    short* dtlH = (short*)(doc + 18 * MB);
    short* dtlL = (short*)(doc + 19 * MB);

    // Scan chunking: NC=32 with state in ws tail if it fits, else NC=16 in d_out.
    int NC = 32;
    size_t stateBytes = (size_t)B_ * NC * DI_ * 16 * 4;        // 16.78 MB
    float *hbuf, *pbuf;
    if (ws_size >= off_tail + 2 * stateBytes) {
        hbuf = (float*)(ws + off_tail);
        pbuf = (float*)(ws + off_tail + stateBytes);
    } else {
        NC = 16;
        hbuf = (float*)(doc);                         // after xpart is dead
        pbuf = (float*)(doc + 8 * MB);
    }

    // 1) pack u + in_proj_w; xz = u @ in_proj_w^T  (M=8192, N=4096, K=1024) -- pipelined
    pack_hl<<<(MROWS * DM_ / 4 + 255) / 256, 256, 0, stream>>>(u, uH, uL, MROWS, MROWS, DM_);
    pack_hl<<<(4096 * DM_ / 4 + 255) / 256, 256, 0, stream>>>(in_proj_w, wiH, wiL, 4096, 4096, DM_);
    gemm_pipe<<<dim3(32 * 32), 512, 0, stream>>>(
        uH, uL, wiH, wiL, xz, /*nblocks=*/32, /*lda=*/DM_, /*NT=*/DM_ / 32, /*ldc=*/2 * DI_);

    // 2) conv + silu -> xcH/xcL (split)
    conv_silu_split<<<(B_ * L_ * DI_ / 4 + 255) / 256, 256, 0, stream>>>(
        xz, conv_w, conv_b, xcH, xcL);

    // 3) x_proj: split-K=4 partials -> reduce (writes dblP + dt-input split)
    pack_hl<<<(128 * DI_ / 4 + 255) / 256, 256, 0, stream>>>(x_proj_w, xpH, xpL, 96, 128, DI_);
    gemm3<3><<<dim3(64, 4), 256, 0, stream>>>(
        (const short*)xcH, (const short*)xcL, xpH, xpL, nullptr, xpart, 64, DI_, DI_ / 4, 128, MROWS);
    xproj_reduce<<<(MROWS * 128) / 256, 256, 0, stream>>>(xpart, dblP, dtlH, dtlL);

    // 4) dt = softplus(dtl @ dt_proj_w^T + b) -> x-half of xz (ldc=4096)
    pack_hl<<<(DI_ * DR_ / 4 + 255) / 256, 256, 0, stream>>>(dt_proj_w, dtwH, dtwL, DI_, DI_, DR_);
    gemm3<1><<<dim3(1024, 1), 256, 0, stream>>>(
        dtlH, dtlL, dtwH, dtwL, dt_proj_b, xz, 64, DR_, DR_, 2 * DI_, MROWS);

    // 5) chunked scan; y (gated) written back into xcH/xcL as hi/lo
    scan_passA<<<dim3(DI_ / 256, NC, B_), 256, 0, stream>>>(xz, xcH, xcL, dblP, A_log, hbuf, pbuf, NC);
    scan_combine<<<(B_ * DI_ * 16) / 256, 256, 0, stream>>>(hbuf, pbuf, NC);
    scan_passC<<<dim3(DI_ / 256, NC, B_), 256, 0, stream>>>(xcH, xcL, xz, dblP, A_log, hbuf, Dv, NC);

    // 6) out = y @ out_proj_w^T  (M=8192, N=1024, K=2048) -- pipelined
    pack_hl<<<(DM_ * DI_ / 4 + 255) / 256, 256, 0, stream>>>(out_proj_w, opH, opL, DM_, DM_, DI_);
    gemm_pipe<<<dim3(32 * 8), 512, 0, stream>>>(
        (const short*)xcH, (const short*)xcL, opH, opL, out, /*nblocks=*/8, /*lda=*/DI_, /*NT=*/DI_ / 32, /*ldc=*/DM_);
}

// Round 10
// 651.086 us; speedup vs baseline: 6.9183x; 1.0182x over previous
//
#include <hip/hip_runtime.h>
#include <hip/hip_bf16.h>
#include <math.h>

// Problem constants
#define B_   4
#define L_   2048
#define DM_  1024
#define DS_  16
#define DI_  2048          // EXP * DM
#define DR_  64            // (DM+15)//16
#define MROWS (B_ * L_)    // 8192

typedef __attribute__((ext_vector_type(8))) short bf16x8;
typedef __attribute__((ext_vector_type(4))) float f32x4;

__device__ inline float softplusf(float x) {
    return (x > 20.f) ? x : log1pf(expf(x));
}

// ---------------- split fp32 -> bf16 hi/lo (x ~= hi + lo, rel err ~2^-17) ----------------
__device__ inline void splitbf(float x, short& h, short& l) {
    unsigned u = __builtin_bit_cast(unsigned, x);
    unsigned r = (u + 0x7FFFu + ((u >> 16) & 1u)) & 0xFFFF0000u;
    h = (short)(r >> 16);
    float lf = x - __builtin_bit_cast(float, r);
    unsigned u2 = __builtin_bit_cast(unsigned, lf);
    unsigned r2 = u2 + 0x7FFFu + ((u2 >> 16) & 1u);
    l = (short)(r2 >> 16);
}

__device__ inline float bfh2f(unsigned hs) {
    return __builtin_bit_cast(float, hs << 16);
}

// X:[R][Kin] f32 -> H,L:[Ralloc][Kin] bf16, rows >= R zeroed
__global__ __launch_bounds__(256) void pack_hl(
    const float* __restrict__ X, short* __restrict__ H, short* __restrict__ L,
    int R, int Ralloc, int Kin)
{
    int idx = blockIdx.x * 256 + threadIdx.x;       // over Ralloc*Kin/4
    int kq = Kin >> 2;
    if (idx >= Ralloc * kq) return;
    int k4 = (idx % kq) * 4, r = idx / kq;
    short4 hi = make_short4(0,0,0,0), lo = make_short4(0,0,0,0);
    if (r < R) {
        float4 v = *(const float4*)&X[(size_t)r * Kin + k4];
        splitbf(v.x, hi.x, lo.x); splitbf(v.y, hi.y, lo.y);
        splitbf(v.z, hi.z, lo.z); splitbf(v.w, hi.w, lo.w);
    }
    size_t base = (size_t)r * Kin + k4;
    *(short4*)&H[base] = hi;
    *(short4*)&L[base] = lo;
}

__device__ inline void gload_lds16(const void* g, void* s) {
    __builtin_amdgcn_global_load_lds(
        (const __attribute__((address_space(1))) void*)g,
        (__attribute__((address_space(3))) void*)s, 16, 0, 0);
}

// ================= Pipelined 4-phase MFMA split-bf16 GEMM (in_proj / out_proj) =========
// C[MxN] = A*B^T via HH+HL+LH, BM=256 BN=128 BK=32, 8 waves 4M x 2N (wave tile 64x64).
// Triple-buffered LDS (3 x 48KB), 2-tile-ahead prefetch, vmcnt(6) at tile boundary only.
// Each K-tile computed in 4 phases (m201-style): {ds-read subtile | stage share ->
// barrier -> lgkmcnt(0) -> setprio+12 MFMA} -- loads span phases, counted waits.
// LDS buf layout (shorts): Ah[0,8192) Al[8192,16384) Bh[16384,20480) Bl[20480,24576).
__device__ inline void stage_full(
    const short* __restrict__ aH, const short* __restrict__ aL,
    const short* __restrict__ bH, const short* __restrict__ bL,
    short* buf, int m0, int n0, int k0, int lda, int tid)
{
    int c0 = tid, c1 = tid + 512;
    int r0 = c0 >> 2, p0 = (c0 & 3) << 3;
    int r1 = c1 >> 2, p1 = (c1 & 3) << 3;
    int ub0 = (tid & ~63) * 8;
    int ub1 = ((tid & ~63) + 512) * 8;
    gload_lds16(&aH[(size_t)(m0 + r0) * lda + k0 + p0], buf + ub0);
    gload_lds16(&aH[(size_t)(m0 + r1) * lda + k0 + p1], buf + ub1);
    gload_lds16(&aL[(size_t)(m0 + r0) * lda + k0 + p0], buf + 8192 + ub0);
    gload_lds16(&aL[(size_t)(m0 + r1) * lda + k0 + p1], buf + 8192 + ub1);
    gload_lds16(&bH[(size_t)(n0 + r0) * lda + k0 + p0], buf + 16384 + ub0);
    gload_lds16(&bL[(size_t)(n0 + r0) * lda + k0 + p0], buf + 20480 + ub0);
}

// Same loads, same issue order, split 2/2/1/1 across phases p=0..3
__device__ inline void stage_part(int p,
    const short* __restrict__ aH, const short* __restrict__ aL,
    const short* __restrict__ bH, const short* __restrict__ bL,
    short* buf, int m0, int n0, int k0, int lda, int tid)
{
    int c0 = tid, c1 = tid + 512;
    int r0 = c0 >> 2, p0o = (c0 & 3) << 3;
    int r1 = c1 >> 2, p1o = (c1 & 3) << 3;
    int ub0 = (tid & ~63) * 8;
    int ub1 = ((tid & ~63) + 512) * 8;
    if (p == 0) {
        gload_lds16(&aH[(size_t)(m0 + r0) * lda + k0 + p0o], buf + ub0);
        gload_lds16(&aH[(size_t)(m0 + r1) * lda + k0 + p1o], buf + ub1);
    } else if (p == 1) {
        gload_lds16(&aL[(size_t)(m0 + r0) * lda + k0 + p0o], buf + 8192 + ub0);
        gload_lds16(&aL[(size_t)(m0 + r1) * lda + k0 + p1o], buf + 8192 + ub1);
    } else if (p == 2) {
        gload_lds16(&bH[(size_t)(n0 + r0) * lda + k0 + p0o], buf + 16384 + ub0);
    } else {
        gload_lds16(&bL[(size_t)(n0 + r0) * lda + k0 + p0o], buf + 20480 + ub0);
    }
}

__global__ __launch_bounds__(512, 2) void gemm_pipe(
    const short* __restrict__ aH, const short* __restrict__ aL,
    const short* __restrict__ bH, const short* __restrict__ bL,
    float* __restrict__ C, int nblocks, int lda, int NT, int ldc)
{
    __shared__ short lds[3 * 24576];
    const int tid = threadIdx.x;
    const int l = tid & 63;
    const int w = tid >> 6;
    const int wm = w & 3;            // 0..3 (M quarter: 64 rows)
    const int wn = w >> 2;           // 0..1 (N half: 64 cols)
    const int lr = l & 15, hk = l >> 4;

    int nwg = gridDim.x;
    int bid = blockIdx.x;
    if ((nwg & 7) == 0) { int cpx = nwg >> 3; bid = (bid & 7) * cpx + (bid >> 3); }
    const int n0 = (bid % nblocks) * 128;
    const int m0 = (bid / nblocks) * 256;

    f32x4 acc[4][4];
    #pragma unroll
    for (int mi = 0; mi < 4; ++mi)
        #pragma unroll
        for (int ni = 0; ni < 4; ++ni) acc[mi][ni] = (f32x4){0.f, 0.f, 0.f, 0.f};

    // prologue: stage tiles 0,1
    stage_full(aH, aL, bH, bL, &lds[0],     m0, n0, 0,  lda, tid);
    stage_full(aH, aL, bH, bL, &lds[24576], m0, n0, 32, lda, tid);
    asm volatile("s_waitcnt vmcnt(6)\ns_barrier" ::: "memory");

    for (int t = 0; t < NT; ++t) {
        short* buf = &lds[(t % 3) * 24576];
        short* sb = (t + 2 < NT) ? &lds[((t + 2) % 3) * 24576] : (short*)0;
        const int k2 = (t + 2) * 32;

        bf16x8 Bh[4], Bl[4];
        #pragma unroll
        for (int p = 0; p < 4; ++p) {
            // --- ds-read this phase's subtile ---
            if (p == 0) {
                #pragma unroll
                for (int ni = 0; ni < 4; ++ni) {
                    int off = 16384 + (wn * 64 + ni * 16 + lr) * 32 + hk * 8;
                    Bh[ni] = *(const bf16x8*)&buf[off];
                    Bl[ni] = *(const bf16x8*)&buf[off + 4096];
                }
            }
            int aoff = (wm * 64 + p * 16 + lr) * 32 + hk * 8;
            bf16x8 Ahp = *(const bf16x8*)&buf[aoff];
            bf16x8 Alp = *(const bf16x8*)&buf[aoff + 8192];

            // --- issue this phase's share of tile t+2 staging ---
            if (sb) stage_part(p, aH, aL, bH, bL, sb, m0, n0, k2, lda, tid);

            __builtin_amdgcn_s_barrier();
            asm volatile("s_waitcnt lgkmcnt(0)" ::: "memory");

            __builtin_amdgcn_s_setprio(1);
            #pragma unroll
            for (int ni = 0; ni < 4; ++ni) {
                acc[p][ni] = __builtin_amdgcn_mfma_f32_16x16x32_bf16(Ahp, Bh[ni], acc[p][ni], 0, 0, 0);
                acc[p][ni] = __builtin_amdgcn_mfma_f32_16x16x32_bf16(Ahp, Bl[ni], acc[p][ni], 0, 0, 0);
                acc[p][ni] = __builtin_amdgcn_mfma_f32_16x16x32_bf16(Alp, Bh[ni], acc[p][ni], 0, 0, 0);
            }
            __builtin_amdgcn_s_setprio(0);
            if (p < 3) __builtin_amdgcn_s_barrier();
        }

        // tile boundary: counted wait (t+1's 6 loads done; t+2's 6 stay in flight)
        if (t + 1 < NT) {
            if (t + 2 < NT) asm volatile("s_waitcnt vmcnt(6)\ns_barrier" ::: "memory");
            else            asm volatile("s_waitcnt vmcnt(0)\ns_barrier" ::: "memory");
        }
    }

    #pragma unroll
    for (int mi = 0; mi < 4; ++mi)
        #pragma unroll
        for (int ni = 0; ni < 4; ++ni) {
            int col = n0 + wn * 64 + ni * 16 + lr;
            int rowb = m0 + wm * 64 + mi * 16 + hk * 4;
            #pragma unroll
            for (int j = 0; j < 4; ++j)
                C[(size_t)(rowb + j) * ldc + col] = acc[mi][ni][j];
        }
}

// ================= old fused GEMM (kept for x_proj split-K and dt) =================
template<int EPI>
__global__ __launch_bounds__(256) void gemm3(
    const short* __restrict__ aH, const short* __restrict__ aL,
    const short* __restrict__ bH, const short* __restrict__ bL,
    const float* __restrict__ bias, float* __restrict__ C,
    int mblocks, int lda, int kLen, int ldc, int M)
{
    __shared__ short AsH[128 * 32];
    __shared__ short AsL[128 * 32];
    __shared__ short BsH[128 * 32];
    __shared__ short BsL[128 * 32];

    const int tid = threadIdx.x;
    const int l  = tid & 63;
    const int wr = (tid >> 6) >> 1, wc = (tid >> 6) & 1;
    const int lr = l & 15, lk = l >> 4;

    int nwg = gridDim.x;
    int bid = blockIdx.x;
    if ((nwg & 7) == 0) { int cpx = nwg >> 3; bid = (bid & 7) * cpx + (bid >> 3); }
    const int m0 = (bid % mblocks) * 128;
    const int n0 = (bid / mblocks) * 128;
    const int kOff = blockIdx.y * kLen;

    f32x4 acc[4][4];
    #pragma unroll
    for (int mi = 0; mi < 4; ++mi)
        #pragma unroll
        for (int ni = 0; ni < 4; ++ni) acc[mi][ni] = (f32x4){0.f, 0.f, 0.f, 0.f};

    for (int k0 = 0; k0 < kLen; k0 += 32) {
        int kk = kOff + k0;
        #pragma unroll
        for (int i = 0; i < 2; ++i) {
            int e = i * 256 + tid;
            int row = e >> 2, cc = (e & 3) * 8;
            int sbase = (i * 256 + (tid & ~63)) * 8;
            size_t offA = (size_t)(m0 + row) * lda + kk + cc;
            size_t offB = (size_t)(n0 + row) * lda + kk + cc;
            gload_lds16(&aH[offA], &AsH[sbase]);
            gload_lds16(&aL[offA], &AsL[sbase]);
            gload_lds16(&bH[offB], &BsH[sbase]);
            gload_lds16(&bL[offB], &BsL[sbase]);
        }
        __syncthreads();

        bf16x8 bfh[4], bfl[4];
        #pragma unroll
        for (int ni = 0; ni < 4; ++ni) {
            int boff = (wc * 64 + ni * 16 + lr) * 32 + lk * 8;
            bfh[ni] = *(const bf16x8*)&BsH[boff];
            bfl[ni] = *(const bf16x8*)&BsL[boff];
        }
        #pragma unroll
        for (int mi = 0; mi < 4; ++mi) {
            int aoff = (wr * 64 + mi * 16 + lr) * 32 + lk * 8;
            bf16x8 ah = *(const bf16x8*)&AsH[aoff];
            bf16x8 al = *(const bf16x8*)&AsL[aoff];
            #pragma unroll
            for (int ni = 0; ni < 4; ++ni) {
                acc[mi][ni] = __builtin_amdgcn_mfma_f32_16x16x32_bf16(ah, bfh[ni], acc[mi][ni], 0, 0, 0);
                acc[mi][ni] = __builtin_amdgcn_mfma_f32_16x16x32_bf16(ah, bfl[ni], acc[mi][ni], 0, 0, 0);
                acc[mi][ni] = __builtin_amdgcn_mfma_f32_16x16x32_bf16(al, bfh[ni], acc[mi][ni], 0, 0, 0);
            }
        }
        __syncthreads();
    }

    float* Cp = C;
    if (EPI == 3) Cp = C + (size_t)blockIdx.y * M * ldc;

    #pragma unroll
    for (int mi = 0; mi < 4; ++mi)
        #pragma unroll
        for (int ni = 0; ni < 4; ++ni) {
            int col  = n0 + wc * 64 + ni * 16 + lr;
            int rowb = m0 + wr * 64 + mi * 16 + lk * 4;
            #pragma unroll
            for (int j = 0; j < 4; ++j) {
                float v = acc[mi][ni][j];
                int row = rowb + j;
                if (EPI == 1) v = softplusf(v + bias[col]);
                Cp[(size_t)row * ldc + col] = v;
            }
        }
}

// ---------------- x_proj split-K reduce ----------------
__global__ __launch_bounds__(256) void xproj_reduce(
    const float* __restrict__ part, float* __restrict__ dblP,
    short* __restrict__ dtlH, short* __restrict__ dtlL)
{
    int idx = blockIdx.x * 256 + threadIdx.x;
    if (idx >= MROWS * 128) return;
    int col = idx & 127, row = idx >> 7;
    const size_t S = (size_t)MROWS * 128;
    float s = part[idx] + part[idx + S] + part[idx + 2 * S] + part[idx + 3 * S];
    if (col < 96) dblP[(size_t)row * 96 + col] = s;
    if (col < 64) {
        short h, lo; splitbf(s, h, lo);
        dtlH[(size_t)row * 64 + col] = h;
        dtlL[(size_t)row * 64 + col] = lo;
    }
}

// ---------------- Depthwise causal conv (DC=4) + SiLU, output split hi/lo ----------------
__global__ __launch_bounds__(256) void conv_silu_split(
    const float* __restrict__ xz, const float* __restrict__ cw,
    const float* __restrict__ cb, ushort* __restrict__ xcH, ushort* __restrict__ xcL)
{
    int t = blockIdx.x * 256 + threadIdx.x;
    if (t >= B_ * L_ * DI_ / 4) return;
    int d4 = (t & (DI_ / 4 - 1)) * 4;
    int ll = (t >> 9) & (L_ - 1);
    int b  = t >> 20;

    float4 w0 = *(const float4*)&cw[(d4 + 0) * 4];
    float4 w1 = *(const float4*)&cw[(d4 + 1) * 4];
    float4 w2 = *(const float4*)&cw[(d4 + 2) * 4];
    float4 w3 = *(const float4*)&cw[(d4 + 3) * 4];
    float4 bb = *(const float4*)&cb[d4];
    float a0 = bb.x, a1 = bb.y, a2 = bb.z, a3 = bb.w;

    size_t rb = (size_t)(b * L_) * 4096 + d4;
    if (ll >= 3) { float4 x = *(const float4*)&xz[rb + (size_t)(ll - 3) * 4096];
                   a0 += x.x * w0.x; a1 += x.y * w1.x; a2 += x.z * w2.x; a3 += x.w * w3.x; }
    if (ll >= 2) { float4 x = *(const float4*)&xz[rb + (size_t)(ll - 2) * 4096];
                   a0 += x.x * w0.y; a1 += x.y * w1.y; a2 += x.z * w2.y; a3 += x.w * w3.y; }
    if (ll >= 1) { float4 x = *(const float4*)&xz[rb + (size_t)(ll - 1) * 4096];
                   a0 += x.x * w0.z; a1 += x.y * w1.z; a2 += x.z * w2.z; a3 += x.w * w3.z; }
    {            float4 x = *(const float4*)&xz[rb + (size_t)ll * 4096];
                   a0 += x.x * w0.w; a1 += x.y * w1.w; a2 += x.z * w2.w; a3 += x.w * w3.w; }

    a0 *= 1.f / (1.f + __expf(-a0));
    a1 *= 1.f / (1.f + __expf(-a1));
    a2 *= 1.f / (1.f + __expf(-a2));
    a3 *= 1.f / (1.f + __expf(-a3));

    short4 hi, lo;
    splitbf(a0, hi.x, lo.x); splitbf(a1, hi.y, lo.y);
    splitbf(a2, hi.z, lo.z); splitbf(a3, hi.w, lo.w);
    size_t oidx = (size_t)(b * L_ + ll) * DI_ + d4;
    *(short4*)&xcH[oidx] = hi;
    *(short4*)&xcL[oidx] = lo;
}

// ---------------- Chunked selective scan ----------------
__global__ __launch_bounds__(256) void scan_passA(
    const float* __restrict__ xz, const ushort* __restrict__ xcH, const ushort* __restrict__ xcL,
    const float* __restrict__ dbl, const float* __restrict__ A_log,
    float* __restrict__ hbuf, float* __restrict__ pbuf, int NC)
{
    __shared__ float sB[128][16];
    const int CL = L_ / NC;
    const int d = blockIdx.x * 256 + threadIdx.x;
    const int c = blockIdx.y, b = blockIdx.z;
    const int row0 = b * L_ + c * CL;

    for (int e = threadIdx.x; e < CL * 16; e += 256) {
        int tt = e >> 4, n = e & 15;
        sB[tt][n] = dbl[(size_t)(row0 + tt) * 96 + 64 + n];
    }
    __syncthreads();

    float A[16], h[16];
    #pragma unroll
    for (int i = 0; i < 16; ++i) { A[i] = -__expf(A_log[d * 16 + i]); h[i] = 0.f; }
    float sumdt = 0.f;

    for (int tt = 0; tt < CL; ++tt) {
        size_t base = (size_t)(row0 + tt);
        float dtv = xz[base * 4096 + d];
        float xv  = bfh2f(xcH[base * 2048 + d]) + bfh2f(xcL[base * 2048 + d]);
        float dtx = dtv * xv;
        sumdt += dtv;
        #pragma unroll
        for (int i = 0; i < 16; ++i) {
            float dA = __expf(dtv * A[i]);
            h[i] = h[i] * dA + dtx * sB[tt][i];
        }
    }

    size_t sidx = (((size_t)b * NC + c) * DI_ + d) * 16;
    #pragma unroll
    for (int i = 0; i < 16; i += 4) {
        *(float4*)&hbuf[sidx + i] = make_float4(h[i], h[i+1], h[i+2], h[i+3]);
        *(float4*)&pbuf[sidx + i] = make_float4(__expf(A[i]   * sumdt), __expf(A[i+1] * sumdt),
                                                __expf(A[i+2] * sumdt), __expf(A[i+3] * sumdt));
    }
}

__global__ __launch_bounds__(256) void scan_combine(
    float* __restrict__ hbuf, const float* __restrict__ pbuf, int NC)
{
    int g = blockIdx.x * 256 + threadIdx.x;
    int n = g & 15;
    int d = (g >> 4) & (DI_ - 1);
    int b = g >> 15;
    float hin = 0.f;
    for (int c = 0; c < NC; ++c) {
        size_t idx = (((size_t)b * NC + c) * DI_ + d) * 16 + n;
        float ho = hbuf[idx], p = pbuf[idx];
        hbuf[idx] = hin;
        hin = ho + p * hin;
    }
}

__global__ __launch_bounds__(256) void scan_passC(
    ushort* __restrict__ xcH, ushort* __restrict__ xcL, const float* __restrict__ xz,
    const float* __restrict__ dbl, const float* __restrict__ A_log,
    const float* __restrict__ hbuf, const float* __restrict__ Dp, int NC)
{
    __shared__ float sBC[128][32];
    const int CL = L_ / NC;
    const int d = blockIdx.x * 256 + threadIdx.x;
    const int c = blockIdx.y, b = blockIdx.z;
    const int row0 = b * L_ + c * CL;

    for (int e = threadIdx.x; e < CL * 32; e += 256) {
        int tt = e >> 5, k = e & 31;
        sBC[tt][k] = dbl[(size_t)(row0 + tt) * 96 + 64 + k];
    }
    __syncthreads();

    float A[16], h[16];
    size_t sidx = (((size_t)b * NC + c) * DI_ + d) * 16;
    #pragma unroll
    for (int i = 0; i < 16; i += 4) {
        float4 v = *(const float4*)&hbuf[sidx + i];
        h[i] = v.x; h[i+1] = v.y; h[i+2] = v.z; h[i+3] = v.w;
    }
    #pragma unroll
    for (int i = 0; i < 16; ++i) A[i] = -__expf(A_log[d * 16 + i]);
    const float Dd = Dp[d];

    for (int tt = 0; tt < CL; ++tt) {
        size_t base = (size_t)(row0 + tt);
        float dtv = xz[base * 4096 + d];
        float xv  = bfh2f(xcH[base * 2048 + d]) + bfh2f(xcL[base * 2048 + d]);
        float zv  = xz[base * 4096 + 2048 + d];
        float dtx = dtv * xv;
        float y = 0.f;
        #pragma unroll
        for (int i = 0; i < 16; ++i) {
            float dA = __expf(dtv * A[i]);
            h[i] = h[i] * dA + dtx * sBC[tt][i];
            y = fmaf(h[i], sBC[tt][16 + i], y);
        }
        float yt = y + xv * Dd;
        float sig = 1.f / (1.f + __expf(-zv));
        float ov = yt * (zv * sig);
        short hh, lo; splitbf(ov, hh, lo);
        xcH[base * 2048 + d] = (ushort)hh;
        xcL[base * 2048 + d] = (ushort)lo;
    }
}

// ---------------- Launch ----------------
extern "C" void kernel_launch(void* const* d_in, const int* in_sizes, int n_in,
                              void* d_out, int out_size, void* d_ws, size_t ws_size,
                              hipStream_t stream)
{
    const float* u         = (const float*)d_in[0];
    const float* in_proj_w = (const float*)d_in[1];
    const float* conv_w    = (const float*)d_in[2];
    const float* conv_b    = (const float*)d_in[3];
    const float* x_proj_w  = (const float*)d_in[4];
    const float* dt_proj_w = (const float*)d_in[5];
    const float* dt_proj_b = (const float*)d_in[6];
    const float* A_log     = (const float*)d_in[7];
    const float* Dv        = (const float*)d_in[8];
    const float* out_proj_w= (const float*)d_in[9];
    float* out = (float*)d_out;

    const size_t MB = 1024ull * 1024ull;
    char* ws = (char*)d_ws;
    // ws (195 MiB fixed): xz f32 @0 (128M) | xcH bf16 @128M (32M) | xcL @160M (32M) | dblP @192M (3M)
    float*  xz   = (float*)(ws);
    ushort* xcH  = (ushort*)(ws + 128 * MB);
    ushort* xcL  = (ushort*)(ws + 160 * MB);
    float*  dblP = (float*)(ws + 192 * MB);
    short*  uH   = (short*)(ws + 128 * MB);           // 16 MiB (dead after in_proj)
    short*  uL   = (short*)(ws + 144 * MB);           // 16 MiB
    short*  wiH  = (short*)(ws + 160 * MB);           //  8 MiB
    short*  wiL  = (short*)(ws + 168 * MB);           //  8 MiB
    short*  opH  = (short*)(ws);                      //  4 MiB (xz dead post-scan)
    short*  opL  = (short*)(ws + 4 * MB);             //  4 MiB
    size_t off_tail = 195 * MB;

    // d_out (32 MiB) scratch until final GEMM overwrites it all
    char* doc = (char*)d_out;
    float* xpart = (float*)(doc);                     // 16M (x_proj partials)
    short* xpH  = (short*)(doc + 16 * MB);
    short* xpL  = (short*)(doc + 16 * MB + 512 * 1024);
    short* dtwH = (short*)(doc + 17 * MB);
    short* dtwL = (short*)(doc + 17 * MB + 256 * 1024);
    short* dtlH = (short*)(doc + 18 * MB);
    short* dtlL = (short*)(doc + 19 * MB);

    // Scan chunking: NC=32 with state in ws tail if it fits, else NC=16 in d_out.
    int NC = 32;
    size_t stateBytes = (size_t)B_ * NC * DI_ * 16 * 4;        // 16.78 MB
    float *hbuf, *pbuf;
    if (ws_size >= off_tail + 2 * stateBytes) {
        hbuf = (float*)(ws + off_tail);
        pbuf = (float*)(ws + off_tail + stateBytes);
    } else {
        NC = 16;
        hbuf = (float*)(doc);                         // after xpart is dead
        pbuf = (float*)(doc + 8 * MB);
    }

    // 1) pack u + in_proj_w; xz = u @ in_proj_w^T  (M=8192, N=4096, K=1024) -- pipelined
    pack_hl<<<(MROWS * DM_ / 4 + 255) / 256, 256, 0, stream>>>(u, uH, uL, MROWS, MROWS, DM_);
    pack_hl<<<(4096 * DM_ / 4 + 255) / 256, 256, 0, stream>>>(in_proj_w, wiH, wiL, 4096, 4096, DM_);
    gemm_pipe<<<dim3(32 * 32), 512, 0, stream>>>(
        uH, uL, wiH, wiL, xz, /*nblocks=*/32, /*lda=*/DM_, /*NT=*/DM_ / 32, /*ldc=*/2 * DI_);

    // 2) conv + silu -> xcH/xcL (split)
    conv_silu_split<<<(B_ * L_ * DI_ / 4 + 255) / 256, 256, 0, stream>>>(
        xz, conv_w, conv_b, xcH, xcL);

    // 3) x_proj: split-K=4 partials -> reduce (writes dblP + dt-input split)
    pack_hl<<<(128 * DI_ / 4 + 255) / 256, 256, 0, stream>>>(x_proj_w, xpH, xpL, 96, 128, DI_);
    gemm3<3><<<dim3(64, 4), 256, 0, stream>>>(
        (const short*)xcH, (const short*)xcL, xpH, xpL, nullptr, xpart, 64, DI_, DI_ / 4, 128, MROWS);
    xproj_reduce<<<(MROWS * 128) / 256, 256, 0, stream>>>(xpart, dblP, dtlH, dtlL);

    // 4) dt = softplus(dtl @ dt_proj_w^T + b) -> x-half of xz (ldc=4096)
    pack_hl<<<(DI_ * DR_ / 4 + 255) / 256, 256, 0, stream>>>(dt_proj_w, dtwH, dtwL, DI_, DI_, DR_);
    gemm3<1><<<dim3(1024, 1), 256, 0, stream>>>(
        dtlH, dtlL, dtwH, dtwL, dt_proj_b, xz, 64, DR_, DR_, 2 * DI_, MROWS);

    // 5) chunked scan; y (gated) written back into xcH/xcL as hi/lo
    scan_passA<<<dim3(DI_ / 256, NC, B_), 256, 0, stream>>>(xz, xcH, xcL, dblP, A_log, hbuf, pbuf, NC);
    scan_combine<<<(B_ * DI_ * 16) / 256, 256, 0, stream>>>(hbuf, pbuf, NC);
    scan_passC<<<dim3(DI_ / 256, NC, B_), 256, 0, stream>>>(xcH, xcL, xz, dblP, A_log, hbuf, Dv, NC);

    // 6) out = y @ out_proj_w^T  (M=8192, N=1024, K=2048) -- pipelined
    pack_hl<<<(DM_ * DI_ / 4 + 255) / 256, 256, 0, stream>>>(out_proj_w, opH, opL, DM_, DM_, DI_);
    gemm_pipe<<<dim3(32 * 8), 512, 0, stream>>>(
        (const short*)xcH, (const short*)xcL, opH, opL, out, /*nblocks=*/8, /*lda=*/DI_, /*NT=*/DI_ / 32, /*ldc=*/DM_);
}